// Round 2
// baseline (467.181 us; speedup 1.0000x reference)
//
#include <hip/hip_runtime.h>
#include <cstdint>
#include <cstddef>

#define DEV __device__ __forceinline__

typedef __attribute__((ext_vector_type(8))) short   short8;
typedef __attribute__((ext_vector_type(8))) __bf16  bf16x8;
typedef __attribute__((ext_vector_type(4))) float   f32x4;

typedef void as1_void __attribute__((address_space(1)));
typedef void as3_void __attribute__((address_space(3)));

DEV short f2b(float f) {
  unsigned u = __float_as_uint(f);
  unsigned r = (u + 0x7fffu + ((u >> 16) & 1u)) >> 16;
  return (short)r;
}
DEV float b2f(short s) {
  return __uint_as_float(((unsigned)(unsigned short)s) << 16);
}

DEV void gload16(const void* g, void* l) {
  __builtin_amdgcn_global_load_lds((as1_void*)g, (as3_void*)l, 16, 0, 0);
}

DEV bf16x8 ld8(const short* p) { return *reinterpret_cast<const bf16x8*>(p); }

// ---------------------------------------------------------------------------
// fp32 -> bf16 convert (vectorized, 8 elems/thread)
// ---------------------------------------------------------------------------
__global__ void convert_kernel(const float* __restrict__ src, short* __restrict__ dst, int n) {
  int i = (blockIdx.x * 256 + threadIdx.x) * 8;
  if (i + 8 > n) return;
  float4 a = *(const float4*)(src + i);
  float4 b = *(const float4*)(src + i + 4);
  short8 o;
  o[0] = f2b(a.x); o[1] = f2b(a.y); o[2] = f2b(a.z); o[3] = f2b(a.w);
  o[4] = f2b(b.x); o[5] = f2b(b.y); o[6] = f2b(b.z); o[7] = f2b(b.w);
  *(short8*)(dst + i) = o;
}

// ---------------------------------------------------------------------------
// Build W_cat[3072][1024] bf16:
//   rows 0..1023    : per-head fmq_w @ Wq_head   (hedgehog q folded in)
//   rows 1024..2047 : per-head fmk_w @ Wk_head
//   rows 2048..3071 : Wv converted
// ---------------------------------------------------------------------------
__global__ void eff_weights_kernel(const float* __restrict__ Wq, const float* __restrict__ Wk,
                                   const float* __restrict__ Wv,
                                   const float* __restrict__ fmq_w, const float* __restrict__ fmk_w,
                                   short* __restrict__ Wcat)
{
  __shared__ float fm[128];
  const int row = blockIdx.x;   // 0..3071
  const int tid = threadIdx.x;  // 256
  if (row < 2048) {
    const float* W   = (row < 1024) ? Wq : Wk;
    const float* fmw = (row < 1024) ? fmq_w : fmk_w;
    const int r = row & 1023, h = r >> 7, e = r & 127;
    if (tid < 128) fm[tid] = fmw[e * 128 + tid];
    __syncthreads();
    for (int c0 = 0; c0 < 1024; c0 += 256) {
      const int cin = c0 + tid;
      float acc = 0.f;
      for (int d = 0; d < 128; ++d)
        acc += fm[d] * W[(h * 128 + d) * 1024 + cin];
      Wcat[(size_t)row * 1024 + cin] = f2b(acc);
    }
  } else {
    const int r = row - 2048;
    for (int c0 = 0; c0 < 1024; c0 += 256)
      Wcat[(size_t)row * 1024 + c0 + tid] = f2b(Wv[(size_t)r * 1024 + c0 + tid]);
  }
}

// ---------------------------------------------------------------------------
// Tiled bf16 MFMA GEMM, C = A @ B^T.  A[M][K], B[N][K] row-major bf16.
// 128x128 tile, 4 waves (2x2 of 64x64), BK=32, global_load_lds staging.
// EPI=0: plain fp32 store to C.
// EPI=1: QKV epilogue -> hedgehog features qf/kf (+ transposed kfT, vT).
// ---------------------------------------------------------------------------
template<int EPI>
__launch_bounds__(256, 2)
__global__ void gemm_bt(const short* __restrict__ A, const short* __restrict__ B,
                        int K, int N, float* __restrict__ C,
                        const float* __restrict__ qb, const float* __restrict__ kb,
                        short* __restrict__ qf, short* __restrict__ kf,
                        short* __restrict__ kfT, short* __restrict__ vT)
{
  __shared__ __align__(16) short lds[8192];   // A tile [128][32], B tile [128][32]
  const int tid = threadIdx.x;
  const int w = tid >> 6, l = tid & 63;
  const int wr = w >> 1, wc = w & 1;
  const int m0 = blockIdx.y * 128, n0 = blockIdx.x * 128;
  short* ldsA = lds;
  short* ldsB = lds + 4096;
  const int srow = w * 32 + (l >> 2);      // staging row (j=0)
  const int skk  = (l & 3) * 8;            // staging k offset (8 bf16 = 16B)

  f32x4 acc[4][4] = {};

  for (int k0 = 0; k0 < K; k0 += 32) {
    __syncthreads();
#pragma unroll
    for (int j = 0; j < 2; ++j) {
      int row = srow + j * 16;
      gload16(A + (size_t)(m0 + row) * K + k0 + skk, ldsA + (w * 2 + j) * 512);
      gload16(B + (size_t)(n0 + row) * K + k0 + skk, ldsB + (w * 2 + j) * 512);
    }
    __syncthreads();
    bf16x8 af[4], bfr[4];
#pragma unroll
    for (int m = 0; m < 4; ++m)
      af[m] = ld8(ldsA + (wr * 64 + m * 16 + (l & 15)) * 32 + (l >> 4) * 8);
#pragma unroll
    for (int n = 0; n < 4; ++n)
      bfr[n] = ld8(ldsB + (wc * 64 + n * 16 + (l & 15)) * 32 + (l >> 4) * 8);
#pragma unroll
    for (int m = 0; m < 4; ++m)
#pragma unroll
      for (int n = 0; n < 4; ++n)
        acc[m][n] = __builtin_amdgcn_mfma_f32_16x16x32_bf16(af[m], bfr[n], acc[m][n], 0, 0, 0);
  }

  if constexpr (EPI == 0) {
#pragma unroll
    for (int m = 0; m < 4; ++m)
#pragma unroll
      for (int n = 0; n < 4; ++n)
#pragma unroll
        for (int r = 0; r < 4; ++r) {
          int row = m0 + wr * 64 + m * 16 + (l >> 4) * 4 + r;
          int col = n0 + wc * 64 + n * 16 + (l & 15);
          C[(size_t)row * N + col] = acc[m][n][r];
        }
  } else {
#pragma unroll
    for (int n = 0; n < 4; ++n) {
      const int col = n0 + wc * 64 + n * 16 + (l & 15);
      const int seg = col >> 10;          // 0=q, 1=k, 2=v
      const int e   = col & 127;
      const int h   = (col >> 7) & 7;
#pragma unroll
      for (int m = 0; m < 4; ++m)
#pragma unroll
        for (int r = 0; r < 4; ++r) {
          const int t   = m0 + wr * 64 + m * 16 + (l >> 4) * 4 + r;  // global token
          const int b   = t >> 11, tok = t & 2047;
          const int bh  = b * 8 + h, c = tok >> 6, tt = tok & 63;
          const float v = acc[m][n][r];
          if (seg == 0) {
            float y = v + qb[e];
            size_t base = ((size_t)bh * 2048 + tok) * 256;
            qf[base + e]       = f2b(__expf(y)  * 0.0625f);
            qf[base + e + 128] = f2b(__expf(-y) * 0.0625f);
          } else if (seg == 1) {
            float y = v + kb[e];
            float f1 = __expf(y), fneg = __expf(-y);
            size_t base = ((size_t)bh * 2048 + tok) * 256;
            kf[base + e]       = f2b(f1);
            kf[base + e + 128] = f2b(fneg);
            size_t tb = ((size_t)bh * 32 + c) * 256 * 64;
            kfT[tb + (size_t)e * 64 + tt]         = f2b(f1);
            kfT[tb + (size_t)(e + 128) * 64 + tt] = f2b(fneg);
          } else {
            vT[(((size_t)bh * 32 + c) * 128 + e) * 64 + tt] = f2b(v);
          }
        }
    }
  }
}

// ---------------------------------------------------------------------------
// Pass A: per (bh,chunk) GT = V^T @ K  -> [128 v][256 d] bf16
// ---------------------------------------------------------------------------
__launch_bounds__(256, 2)
__global__ void passA_kernel(const short* __restrict__ kfT, const short* __restrict__ vT,
                             short* __restrict__ GT)
{
  const int bhc = blockIdx.x;                 // bh*32 + c
  const int tid = threadIdx.x, w = tid >> 6, l = tid & 63;
  const short* kT = kfT + (size_t)bhc * 256 * 64;
  const short* vt = vT  + (size_t)bhc * 128 * 64;
  short* G = GT + (size_t)bhc * 128 * 256;
#pragma unroll
  for (int mi = 0; mi < 2; ++mi) {
    const int v0 = w * 32 + mi * 16;
    bf16x8 a[2];
#pragma unroll
    for (int ks = 0; ks < 2; ++ks)
      a[ks] = ld8(vt + (v0 + (l & 15)) * 64 + ks * 32 + (l >> 4) * 8);
    f32x4 acc[16] = {};
#pragma unroll
    for (int nt = 0; nt < 16; ++nt)
#pragma unroll
      for (int ks = 0; ks < 2; ++ks) {
        bf16x8 b = ld8(kT + (nt * 16 + (l & 15)) * 64 + ks * 32 + (l >> 4) * 8);
        acc[nt] = __builtin_amdgcn_mfma_f32_16x16x32_bf16(a[ks], b, acc[nt], 0, 0, 0);
      }
#pragma unroll
    for (int nt = 0; nt < 16; ++nt)
#pragma unroll
      for (int r = 0; r < 4; ++r)
        G[(v0 + (l >> 4) * 4 + r) * 256 + nt * 16 + (l & 15)] = f2b(acc[nt][r]);
  }
}

// ---------------------------------------------------------------------------
// In-place exclusive prefix over chunks: GT[bh][c] <- sum_{c'<c} GT[bh][c']
// ---------------------------------------------------------------------------
__global__ void prefix_kernel(short* __restrict__ GT) {
  const int bh = blockIdx.x >> 3, slab = blockIdx.x & 7;
  const int tid = threadIdx.x;
  short* base = GT + (size_t)bh * 32 * 32768 + slab * 4096 + tid * 16;
  float acc[16] = {};
  for (int c = 0; c < 32; ++c) {
    short* p = base + (size_t)c * 32768;
    short8 g0 = *(const short8*)p;
    short8 g1 = *(const short8*)(p + 8);
    short8 s0, s1;
#pragma unroll
    for (int j = 0; j < 8; ++j) { s0[j] = f2b(acc[j]); s1[j] = f2b(acc[8 + j]); }
    *(short8*)p = s0;
    *(short8*)(p + 8) = s1;
#pragma unroll
    for (int j = 0; j < 8; ++j) { acc[j] += b2f(g0[j]); acc[8 + j] += b2f(g1[j]); }
  }
}

// ---------------------------------------------------------------------------
// Pass C: per (bh,chunk): O = tril(Q K^T) V + Q S, then fused RMSNorm,
// write o_norm[token][h*128+v] bf16.
// ---------------------------------------------------------------------------
__launch_bounds__(256, 2)
__global__ void passC_kernel(const short* __restrict__ qf, const short* __restrict__ kf,
                             const short* __restrict__ vT, const short* __restrict__ ST,
                             const float* __restrict__ rms_w, short* __restrict__ o_n)
{
  const int bhc = blockIdx.x, bh = bhc >> 5, c = bhc & 31;
  const int tid = threadIdx.x, w = tid >> 6, l = tid & 63;
  __shared__ __align__(16) short attn[64 * 72];
  const short* q  = qf + ((size_t)bh * 2048 + c * 64) * 256;
  const short* k  = kf + ((size_t)bh * 2048 + c * 64) * 256;
  const short* vt = vT + (size_t)bhc * 128 * 64;
  const short* st = ST + (size_t)bhc * 128 * 256;
  const int r0 = w * 16;

  // intra-chunk scores (Q Kf^T), K-dim = DF = 256
  f32x4 s[4] = {};
#pragma unroll
  for (int ks = 0; ks < 8; ++ks) {
    bf16x8 a = ld8(q + (r0 + (l & 15)) * 256 + ks * 32 + (l >> 4) * 8);
#pragma unroll
    for (int nt = 0; nt < 4; ++nt) {
      bf16x8 b = ld8(k + (nt * 16 + (l & 15)) * 256 + ks * 32 + (l >> 4) * 8);
      s[nt] = __builtin_amdgcn_mfma_f32_16x16x32_bf16(a, b, s[nt], 0, 0, 0);
    }
  }
#pragma unroll
  for (int nt = 0; nt < 4; ++nt)
#pragma unroll
    for (int r = 0; r < 4; ++r) {
      int rr = r0 + (l >> 4) * 4 + r;     // row within chunk
      int tt = nt * 16 + (l & 15);        // col (key token) within chunk
      attn[rr * 72 + tt] = (tt <= rr) ? f2b(s[nt][r]) : (short)0;
    }
  __syncthreads();

  f32x4 o[8] = {};
  // intra: attn @ V  (K-dim = 64 tokens)
#pragma unroll
  for (int ks = 0; ks < 2; ++ks) {
    bf16x8 a = ld8(attn + (r0 + (l & 15)) * 72 + ks * 32 + (l >> 4) * 8);
#pragma unroll
    for (int nt = 0; nt < 8; ++nt) {
      bf16x8 b = ld8(vt + (nt * 16 + (l & 15)) * 64 + ks * 32 + (l >> 4) * 8);
      o[nt] = __builtin_amdgcn_mfma_f32_16x16x32_bf16(a, b, o[nt], 0, 0, 0);
    }
  }
  // inter: Q @ S  (K-dim = DF = 256), S^T stored [v][d]
#pragma unroll
  for (int ks = 0; ks < 8; ++ks) {
    bf16x8 a = ld8(q + (r0 + (l & 15)) * 256 + ks * 32 + (l >> 4) * 8);
#pragma unroll
    for (int nt = 0; nt < 8; ++nt) {
      bf16x8 b = ld8(st + (nt * 16 + (l & 15)) * 256 + ks * 32 + (l >> 4) * 8);
      o[nt] = __builtin_amdgcn_mfma_f32_16x16x32_bf16(a, b, o[nt], 0, 0, 0);
    }
  }

  // fused RMSNorm over DV=128 + store bf16
  const int b = bh >> 3, h = bh & 7;
#pragma unroll
  for (int r = 0; r < 4; ++r) {
    float ss = 0.f;
#pragma unroll
    for (int nt = 0; nt < 8; ++nt) ss += o[nt][r] * o[nt][r];
    ss += __shfl_xor(ss, 1);
    ss += __shfl_xor(ss, 2);
    ss += __shfl_xor(ss, 4);
    ss += __shfl_xor(ss, 8);
    float sc = rsqrtf(ss * (1.0f / 128.0f) + 1e-5f);
    int tok = c * 64 + r0 + (l >> 4) * 4 + r;
    size_t ob = ((size_t)b * 2048 + tok) * 1024 + h * 128;
#pragma unroll
    for (int nt = 0; nt < 8; ++nt) {
      int vcol = nt * 16 + (l & 15);
      o_n[ob + vcol] = f2b(o[nt][r] * sc * rms_w[vcol]);
    }
  }
}

// ---------------------------------------------------------------------------
extern "C" void kernel_launch(void* const* d_in, const int* in_sizes, int n_in,
                              void* d_out, int out_size, void* d_ws, size_t ws_size,
                              hipStream_t stream)
{
  const float* x     = (const float*)d_in[0];
  const float* Wq    = (const float*)d_in[1];
  const float* Wk    = (const float*)d_in[2];
  const float* Wv    = (const float*)d_in[3];
  const float* Wo    = (const float*)d_in[4];
  const float* fmq_w = (const float*)d_in[5];
  const float* fmq_b = (const float*)d_in[6];
  const float* fmk_w = (const float*)d_in[7];
  const float* fmk_b = (const float*)d_in[8];
  const float* rms_w = (const float*)d_in[9];
  float* out = (float*)d_out;

  char* ws = (char*)d_ws;
  short* x_b  = (short*)(ws);                  // 16.78 MB  (reused as o_norm later)
  short* Wcat = (short*)(ws + 16777216);       //  6.29 MB
  short* Wo_b = (short*)(ws + 23068672);       //  2.10 MB
  short* qf   = (short*)(ws + 25165824);       // 33.55 MB
  short* kf   = (short*)(ws + 58720256);       // 33.55 MB
  short* kfT  = (short*)(ws + 92274688);       // 33.55 MB
  short* vT   = (short*)(ws + 125829120);      // 16.78 MB
  short* GT   = (short*)(ws + 142606336);      // 33.55 MB   (becomes S^T in-place)
  short* o_n  = x_b;                           // alias: x_b dead after QKV GEMM

  convert_kernel<<<4096, 256, 0, stream>>>(x, x_b, 8388608);
  convert_kernel<<<512, 256, 0, stream>>>(Wo, Wo_b, 1048576);
  eff_weights_kernel<<<3072, 256, 0, stream>>>(Wq, Wk, Wv, fmq_w, fmk_w, Wcat);
  gemm_bt<1><<<dim3(24, 64), 256, 0, stream>>>(x_b, Wcat, 1024, 3072, nullptr,
                                               fmq_b, fmk_b, qf, kf, kfT, vT);
  passA_kernel<<<1024, 256, 0, stream>>>(kfT, vT, GT);
  prefix_kernel<<<256, 256, 0, stream>>>(GT);
  passC_kernel<<<1024, 256, 0, stream>>>(qf, kf, vT, GT, rms_w, o_n);
  gemm_bt<0><<<dim3(8, 64), 256, 0, stream>>>(o_n, Wo_b, 1024, 1024, out,
                                              nullptr, nullptr, nullptr, nullptr,
                                              nullptr, nullptr);
}

// Round 3
// 433.485 us; speedup vs baseline: 1.0777x; 1.0777x over previous
//
#include <hip/hip_runtime.h>
#include <cstdint>
#include <cstddef>

#define DEV __device__ __forceinline__

typedef __attribute__((ext_vector_type(8))) short   short8;
typedef __attribute__((ext_vector_type(4))) short   sshort4;
typedef __attribute__((ext_vector_type(8))) __bf16  bf16x8;
typedef __attribute__((ext_vector_type(4))) float   f32x4;

typedef void as1_void __attribute__((address_space(1)));
typedef void as3_void __attribute__((address_space(3)));

DEV short f2b(float f) {
  unsigned u = __float_as_uint(f);
  unsigned r = (u + 0x7fffu + ((u >> 16) & 1u)) >> 16;
  return (short)r;
}
DEV float b2f(short s) {
  return __uint_as_float(((unsigned)(unsigned short)s) << 16);
}

DEV void gload16(const void* g, void* l) {
  __builtin_amdgcn_global_load_lds((as1_void*)g, (as3_void*)l, 16, 0, 0);
}

DEV bf16x8 ld8(const short* p) { return *reinterpret_cast<const bf16x8*>(p); }

// ---------------------------------------------------------------------------
// fp32 -> bf16 convert (vectorized, 8 elems/thread)
// ---------------------------------------------------------------------------
__global__ void convert_kernel(const float* __restrict__ src, short* __restrict__ dst, int n) {
  int i = (blockIdx.x * 256 + threadIdx.x) * 8;
  if (i + 8 > n) return;
  float4 a = *(const float4*)(src + i);
  float4 b = *(const float4*)(src + i + 4);
  short8 o;
  o[0] = f2b(a.x); o[1] = f2b(a.y); o[2] = f2b(a.z); o[3] = f2b(a.w);
  o[4] = f2b(b.x); o[5] = f2b(b.y); o[6] = f2b(b.z); o[7] = f2b(b.w);
  *(short8*)(dst + i) = o;
}

// ---------------------------------------------------------------------------
// Build W_cat rows 0..2047 (q,k with hedgehog fold). 16 e-rows per block so
// each W head-slab (512KB) is fetched 8x less. grid = 2 sel x 8 h x 8 eg.
// ---------------------------------------------------------------------------
__global__ void eff_weights2_kernel(const float* __restrict__ Wq, const float* __restrict__ Wk,
                                    const float* __restrict__ fmq_w, const float* __restrict__ fmk_w,
                                    short* __restrict__ Wcat)
{
  __shared__ float fm[16 * 128];
  const int blk = blockIdx.x;
  const int sel = blk >> 6, h = (blk >> 3) & 7, eg = blk & 7;
  const float* W   = sel ? Wk : Wq;
  const float* fmw = sel ? fmk_w : fmq_w;
  const int tid = threadIdx.x;
  const int e0 = eg * 16;
  for (int i = tid; i < 2048; i += 256) fm[i] = fmw[e0 * 128 + i];
  __syncthreads();
  float acc[16][4] = {};
  for (int d = 0; d < 128; d += 4) {
    f32x4 w0 = *(const f32x4*)(W + (size_t)(h * 128 + d + 0) * 1024 + tid * 4);
    f32x4 w1 = *(const f32x4*)(W + (size_t)(h * 128 + d + 1) * 1024 + tid * 4);
    f32x4 w2 = *(const f32x4*)(W + (size_t)(h * 128 + d + 2) * 1024 + tid * 4);
    f32x4 w3 = *(const f32x4*)(W + (size_t)(h * 128 + d + 3) * 1024 + tid * 4);
#pragma unroll
    for (int e = 0; e < 16; ++e) {
      f32x4 fv = *(const f32x4*)&fm[e * 128 + d];
#pragma unroll
      for (int c = 0; c < 4; ++c)
        acc[e][c] += fv[0] * w0[c] + fv[1] * w1[c] + fv[2] * w2[c] + fv[3] * w3[c];
    }
  }
#pragma unroll
  for (int e = 0; e < 16; ++e) {
    sshort4 o;
#pragma unroll
    for (int c = 0; c < 4; ++c) o[c] = f2b(acc[e][c]);
    *(sshort4*)(Wcat + (size_t)(sel * 1024 + h * 128 + e0 + e) * 1024 + tid * 4) = o;
  }
}

// ---------------------------------------------------------------------------
// Tiled bf16 MFMA GEMM, C = A @ B^T.  A[M][K], B[N][K] row-major bf16.
// 128x128 tile, 4 waves (2x2 of 64x64), BK=32, global_load_lds staging with
// bank-conflict-free XOR swizzle (both-sides: pre-swizzled global source +
// swizzled ds_read).  Epilogues staged through LDS for coalesced stores.
// EPI=0: fp32 C.  EPI=1: hedgehog features qf/kf (+ transposed kfT, vT).
// ---------------------------------------------------------------------------
template<int EPI>
__launch_bounds__(256, 3)
__global__ void gemm_bt(const short* __restrict__ A, const short* __restrict__ B,
                        int K, int N, float* __restrict__ C,
                        const float* __restrict__ qb, const float* __restrict__ kb,
                        short* __restrict__ qf, short* __restrict__ kf,
                        short* __restrict__ kfT, short* __restrict__ vT)
{
  // union: main loop uses first 16 KB as A/B staging; epilogue uses 33 KB as
  // a 64x132 f32 tile (two halves).
  __shared__ __align__(16) char smem[64 * 132 * 4];
  short* lds = (short*)smem;
  float* ep  = (float*)smem;

  const int tid = threadIdx.x;
  const int w = tid >> 6, l = tid & 63;
  const int wr = w >> 1, wc = w & 1;

  // XCD-aware bijective block swizzle (nwg % 8 == 0 for both call sites)
  const int nbx = gridDim.x;
  const int orig = blockIdx.y * nbx + blockIdx.x;
  const int cpx = (nbx * gridDim.y) >> 3;
  const int wg = (orig & 7) * cpx + (orig >> 3);
  const int m0 = (wg / nbx) * 128, n0 = (wg % nbx) * 128;

  short* ldsA = lds;
  short* ldsB = lds + 4096;
  const int srow = w * 32 + (l >> 2);      // staging row (j=0)

  f32x4 acc[4][4] = {};

  for (int k0 = 0; k0 < K; k0 += 32) {
    __syncthreads();
#pragma unroll
    for (int j = 0; j < 2; ++j) {
      const int row = srow + j * 16;
      const int sl = (((l & 3) ^ ((row >> 1) & 3))) * 8;   // pre-swizzled source slot
      gload16(A + (size_t)(m0 + row) * K + k0 + sl, ldsA + (w * 2 + j) * 512);
      gload16(B + (size_t)(n0 + row) * K + k0 + sl, ldsB + (w * 2 + j) * 512);
    }
    __syncthreads();
    bf16x8 af[4], bfr[4];
#pragma unroll
    for (int m = 0; m < 4; ++m) {
      const int ra = wr * 64 + m * 16 + (l & 15);
      af[m] = ld8(ldsA + ra * 32 + (((l >> 4) ^ ((ra >> 1) & 3))) * 8);
    }
#pragma unroll
    for (int n = 0; n < 4; ++n) {
      const int rb = wc * 64 + n * 16 + (l & 15);
      bfr[n] = ld8(ldsB + rb * 32 + (((l >> 4) ^ ((rb >> 1) & 3))) * 8);
    }
#pragma unroll
    for (int m = 0; m < 4; ++m)
#pragma unroll
      for (int n = 0; n < 4; ++n)
        acc[m][n] = __builtin_amdgcn_mfma_f32_16x16x32_bf16(af[m], bfr[n], acc[m][n], 0, 0, 0);
  }

  // ---------------- epilogue: LDS-staged, coalesced ----------------
  const int seg = (EPI == 1) ? (n0 >> 10) : 0;          // 0=q 1=k 2=v
  const int b   = m0 >> 11, tok0 = m0 & 2047, c0 = tok0 >> 6;
  const int h   = (n0 & 1023) >> 7;
  const int bh  = b * 8 + h;

  for (int half = 0; half < 2; ++half) {
    __syncthreads();
    if (wr == half) {
#pragma unroll
      for (int n = 0; n < 4; ++n) {
        const int cl = wc * 64 + n * 16 + (l & 15);
        float bb = 0.f;
        if constexpr (EPI == 1) bb = (seg == 0) ? qb[cl] : (seg == 1) ? kb[cl] : 0.f;
#pragma unroll
        for (int m = 0; m < 4; ++m)
#pragma unroll
          for (int r = 0; r < 4; ++r) {
            const int rl = m * 16 + (l >> 4) * 4 + r;
            ep[rl * 132 + (cl ^ ((rl & 7) << 2))] = acc[m][n][r] + bb;
          }
      }
    }
    __syncthreads();

    if constexpr (EPI == 0) {
#pragma unroll
      for (int it = 0; it < 8; ++it) {
        const int tl = it * 8 + (tid >> 5);
        const int q = tid & 31;
        f32x4 v4 = *(const f32x4*)&ep[tl * 132 + ((q * 4) ^ ((tl & 7) << 2))];
        *(f32x4*)(C + (size_t)(m0 + half * 64 + tl) * N + n0 + q * 4) = v4;
      }
    } else {
      if (seg <= 1) {
        short* dst = (seg == 0) ? qf : kf;
        const float sc = (seg == 0) ? 0.0625f : 1.0f;
#pragma unroll
        for (int it = 0; it < 8; ++it) {
          const int tl = it * 8 + (tid >> 5);
          const int q = tid & 31;
          f32x4 y4 = *(const f32x4*)&ep[tl * 132 + ((q * 4) ^ ((tl & 7) << 2))];
          sshort4 sp, sm;
#pragma unroll
          for (int j = 0; j < 4; ++j) {
            sp[j] = f2b(__expf(y4[j]) * sc);
            sm[j] = f2b(__expf(-y4[j]) * sc);
          }
          short* rowp = dst + ((size_t)bh * 2048 + tok0 + half * 64 + tl) * 256;
          *(sshort4*)(rowp + q * 4)       = sp;
          *(sshort4*)(rowp + 128 + q * 4) = sm;
        }
        if (seg == 1) {
#pragma unroll
          for (int p2 = 0; p2 < 8; ++p2) {
            const int r = p2 * 32 + (tid >> 3);
            const int e = r & 127, sg = r >> 7;
            const int oct = (tid & 7) * 8;
            short8 o;
#pragma unroll
            for (int i = 0; i < 8; ++i) {
              float y = ep[(oct + i) * 132 + (e ^ (i << 2))];
              o[i] = f2b(__expf(sg ? -y : y));
            }
            *(short8*)(kfT + (((size_t)bh * 32 + c0 + half) * 256 + r) * 64 + oct) = o;
          }
        }
      } else {
#pragma unroll
        for (int p2 = 0; p2 < 4; ++p2) {
          const int r = p2 * 32 + (tid >> 3);
          const int oct = (tid & 7) * 8;
          short8 o;
#pragma unroll
          for (int i = 0; i < 8; ++i)
            o[i] = f2b(ep[(oct + i) * 132 + (r ^ (i << 2))]);
          *(short8*)(vT + (((size_t)bh * 32 + c0 + half) * 128 + r) * 64 + oct) = o;
        }
      }
    }
  }
}

// ---------------------------------------------------------------------------
// Pass A: per (bh,chunk) GT = V^T @ K  -> [128 v][256 d] bf16
// ---------------------------------------------------------------------------
__launch_bounds__(256, 2)
__global__ void passA_kernel(const short* __restrict__ kfT, const short* __restrict__ vT,
                             short* __restrict__ GT)
{
  const int bhc = blockIdx.x;                 // bh*32 + c
  const int tid = threadIdx.x, w = tid >> 6, l = tid & 63;
  const short* kT = kfT + (size_t)bhc * 256 * 64;
  const short* vt = vT  + (size_t)bhc * 128 * 64;
  short* G = GT + (size_t)bhc * 128 * 256;
#pragma unroll
  for (int mi = 0; mi < 2; ++mi) {
    const int v0 = w * 32 + mi * 16;
    bf16x8 a[2];
#pragma unroll
    for (int ks = 0; ks < 2; ++ks)
      a[ks] = ld8(vt + (v0 + (l & 15)) * 64 + ks * 32 + (l >> 4) * 8);
    f32x4 acc[16] = {};
#pragma unroll
    for (int nt = 0; nt < 16; ++nt)
#pragma unroll
      for (int ks = 0; ks < 2; ++ks) {
        bf16x8 b = ld8(kT + (nt * 16 + (l & 15)) * 64 + ks * 32 + (l >> 4) * 8);
        acc[nt] = __builtin_amdgcn_mfma_f32_16x16x32_bf16(a[ks], b, acc[nt], 0, 0, 0);
      }
#pragma unroll
    for (int nt = 0; nt < 16; ++nt)
#pragma unroll
      for (int r = 0; r < 4; ++r)
        G[(v0 + (l >> 4) * 4 + r) * 256 + nt * 16 + (l & 15)] = f2b(acc[nt][r]);
  }
}

// ---------------------------------------------------------------------------
// In-place exclusive prefix over chunks: GT[bh][c] <- sum_{c'<c} GT[bh][c']
// 512 blocks (bh x 16 slabs of 2048 shorts); next-chunk load prefetched.
// ---------------------------------------------------------------------------
__global__ void prefix_kernel(short* __restrict__ GT) {
  const int bh = blockIdx.x >> 4, slab = blockIdx.x & 15;
  short* base = GT + (size_t)bh * 32 * 32768 + slab * 2048 + threadIdx.x * 8;
  float acc[8] = {};
  short8 g = *(const short8*)base;
  for (int c = 0; c < 32; ++c) {
    short* p = base + (size_t)c * 32768;
    short8 gn = {};
    if (c < 31) gn = *(const short8*)(p + 32768);
    short8 s;
#pragma unroll
    for (int j = 0; j < 8; ++j) s[j] = f2b(acc[j]);
    *(short8*)p = s;
#pragma unroll
    for (int j = 0; j < 8; ++j) acc[j] += b2f(g[j]);
    g = gn;
  }
}

// ---------------------------------------------------------------------------
// Pass C: per (bh,chunk): O = tril(Q K^T) V + Q S, then fused RMSNorm,
// write o_norm[token][h*128+v] bf16.
// ---------------------------------------------------------------------------
__launch_bounds__(256, 2)
__global__ void passC_kernel(const short* __restrict__ qf, const short* __restrict__ kf,
                             const short* __restrict__ vT, const short* __restrict__ ST,
                             const float* __restrict__ rms_w, short* __restrict__ o_n)
{
  const int bhc = blockIdx.x, bh = bhc >> 5, c = bhc & 31;
  const int tid = threadIdx.x, w = tid >> 6, l = tid & 63;
  __shared__ __align__(16) short attn[64 * 72];
  const short* q  = qf + ((size_t)bh * 2048 + c * 64) * 256;
  const short* k  = kf + ((size_t)bh * 2048 + c * 64) * 256;
  const short* vt = vT + (size_t)bhc * 128 * 64;
  const short* st = ST + (size_t)bhc * 128 * 256;
  const int r0 = w * 16;

  // intra-chunk scores (Q Kf^T), K-dim = DF = 256
  f32x4 s[4] = {};
#pragma unroll
  for (int ks = 0; ks < 8; ++ks) {
    bf16x8 a = ld8(q + (r0 + (l & 15)) * 256 + ks * 32 + (l >> 4) * 8);
#pragma unroll
    for (int nt = 0; nt < 4; ++nt) {
      bf16x8 b = ld8(k + (nt * 16 + (l & 15)) * 256 + ks * 32 + (l >> 4) * 8);
      s[nt] = __builtin_amdgcn_mfma_f32_16x16x32_bf16(a, b, s[nt], 0, 0, 0);
    }
  }
#pragma unroll
  for (int nt = 0; nt < 4; ++nt)
#pragma unroll
    for (int r = 0; r < 4; ++r) {
      int rr = r0 + (l >> 4) * 4 + r;     // row within chunk
      int tt = nt * 16 + (l & 15);        // col (key token) within chunk
      attn[rr * 72 + tt] = (tt <= rr) ? f2b(s[nt][r]) : (short)0;
    }
  __syncthreads();

  f32x4 o[8] = {};
  // intra: attn @ V  (K-dim = 64 tokens)
#pragma unroll
  for (int ks = 0; ks < 2; ++ks) {
    bf16x8 a = ld8(attn + (r0 + (l & 15)) * 72 + ks * 32 + (l >> 4) * 8);
#pragma unroll
    for (int nt = 0; nt < 8; ++nt) {
      bf16x8 b = ld8(vt + (nt * 16 + (l & 15)) * 64 + ks * 32 + (l >> 4) * 8);
      o[nt] = __builtin_amdgcn_mfma_f32_16x16x32_bf16(a, b, o[nt], 0, 0, 0);
    }
  }
  // inter: Q @ S  (K-dim = DF = 256), S^T stored [v][d]
#pragma unroll
  for (int ks = 0; ks < 8; ++ks) {
    bf16x8 a = ld8(q + (r0 + (l & 15)) * 256 + ks * 32 + (l >> 4) * 8);
#pragma unroll
    for (int nt = 0; nt < 8; ++nt) {
      bf16x8 b = ld8(st + (nt * 16 + (l & 15)) * 256 + ks * 32 + (l >> 4) * 8);
      o[nt] = __builtin_amdgcn_mfma_f32_16x16x32_bf16(a, b, o[nt], 0, 0, 0);
    }
  }

  // fused RMSNorm over DV=128 + store bf16
  const int b = bh >> 3, h = bh & 7;
#pragma unroll
  for (int r = 0; r < 4; ++r) {
    float ss = 0.f;
#pragma unroll
    for (int nt = 0; nt < 8; ++nt) ss += o[nt][r] * o[nt][r];
    ss += __shfl_xor(ss, 1);
    ss += __shfl_xor(ss, 2);
    ss += __shfl_xor(ss, 4);
    ss += __shfl_xor(ss, 8);
    float sc = rsqrtf(ss * (1.0f / 128.0f) + 1e-5f);
    int tok = c * 64 + r0 + (l >> 4) * 4 + r;
    size_t ob = ((size_t)b * 2048 + tok) * 1024 + h * 128;
#pragma unroll
    for (int nt = 0; nt < 8; ++nt) {
      int vcol = nt * 16 + (l & 15);
      o_n[ob + vcol] = f2b(o[nt][r] * sc * rms_w[vcol]);
    }
  }
}

// ---------------------------------------------------------------------------
extern "C" void kernel_launch(void* const* d_in, const int* in_sizes, int n_in,
                              void* d_out, int out_size, void* d_ws, size_t ws_size,
                              hipStream_t stream)
{
  const float* x     = (const float*)d_in[0];
  const float* Wq    = (const float*)d_in[1];
  const float* Wk    = (const float*)d_in[2];
  const float* Wv    = (const float*)d_in[3];
  const float* Wo    = (const float*)d_in[4];
  const float* fmq_w = (const float*)d_in[5];
  const float* fmq_b = (const float*)d_in[6];
  const float* fmk_w = (const float*)d_in[7];
  const float* fmk_b = (const float*)d_in[8];
  const float* rms_w = (const float*)d_in[9];
  float* out = (float*)d_out;

  char* ws = (char*)d_ws;
  short* x_b  = (short*)(ws);                  // 16.78 MB  (reused as o_norm later)
  short* Wcat = (short*)(ws + 16777216);       //  6.29 MB
  short* Wo_b = (short*)(ws + 23068672);       //  2.10 MB
  short* qf   = (short*)(ws + 25165824);       // 33.55 MB
  short* kf   = (short*)(ws + 58720256);       // 33.55 MB
  short* kfT  = (short*)(ws + 92274688);       // 33.55 MB
  short* vT   = (short*)(ws + 125829120);      // 16.78 MB
  short* GT   = (short*)(ws + 142606336);      // 33.55 MB   (becomes S^T in-place)
  short* o_n  = x_b;                           // alias: x_b dead after QKV GEMM

  convert_kernel<<<4096, 256, 0, stream>>>(x, x_b, 8388608);
  convert_kernel<<<512, 256, 0, stream>>>(Wo, Wo_b, 1048576);
  convert_kernel<<<512, 256, 0, stream>>>(Wv, Wcat + 2097152, 1048576);
  eff_weights2_kernel<<<128, 256, 0, stream>>>(Wq, Wk, fmq_w, fmk_w, Wcat);
  gemm_bt<1><<<dim3(24, 64), 256, 0, stream>>>(x_b, Wcat, 1024, 3072, nullptr,
                                               fmq_b, fmk_b, qf, kf, kfT, vT);
  passA_kernel<<<1024, 256, 0, stream>>>(kfT, vT, GT);
  prefix_kernel<<<512, 256, 0, stream>>>(GT);
  passC_kernel<<<1024, 256, 0, stream>>>(qf, kf, vT, GT, rms_w, o_n);
  gemm_bt<0><<<dim3(8, 64), 256, 0, stream>>>(o_n, Wo_b, 1024, 1024, out,
                                              nullptr, nullptr, nullptr, nullptr,
                                              nullptr, nullptr);
}

// Round 4
// 371.292 us; speedup vs baseline: 1.2583x; 1.1675x over previous
//
#include <hip/hip_runtime.h>
#include <cstdint>
#include <cstddef>

#define DEV __device__ __forceinline__

typedef __attribute__((ext_vector_type(8))) short   short8;
typedef __attribute__((ext_vector_type(4))) short   sshort4;
typedef __attribute__((ext_vector_type(8))) __bf16  bf16x8;
typedef __attribute__((ext_vector_type(4))) float   f32x4;

typedef void as1_void __attribute__((address_space(1)));
typedef void as3_void __attribute__((address_space(3)));

DEV short f2b(float f) {
  unsigned u = __float_as_uint(f);
  unsigned r = (u + 0x7fffu + ((u >> 16) & 1u)) >> 16;
  return (short)r;
}
DEV float b2f(short s) {
  return __uint_as_float(((unsigned)(unsigned short)s) << 16);
}

DEV void gload16(const void* g, void* l) {
  __builtin_amdgcn_global_load_lds((as1_void*)g, (as3_void*)l, 16, 0, 0);
}

DEV bf16x8 ld8(const short* p) { return *reinterpret_cast<const bf16x8*>(p); }

DEV f32x4 mfma16(bf16x8 a, bf16x8 b, f32x4 c) {
  return __builtin_amdgcn_mfma_f32_16x16x32_bf16(a, b, c, 0, 0, 0);
}

// ---------------------------------------------------------------------------
// fp32 -> bf16 convert (vectorized, 8 elems/thread)
// ---------------------------------------------------------------------------
__global__ void convert_kernel(const float* __restrict__ src, short* __restrict__ dst, int n) {
  int i = (blockIdx.x * 256 + threadIdx.x) * 8;
  if (i + 8 > n) return;
  float4 a = *(const float4*)(src + i);
  float4 b = *(const float4*)(src + i + 4);
  short8 o;
  o[0] = f2b(a.x); o[1] = f2b(a.y); o[2] = f2b(a.z); o[3] = f2b(a.w);
  o[4] = f2b(b.x); o[5] = f2b(b.y); o[6] = f2b(b.z); o[7] = f2b(b.w);
  *(short8*)(dst + i) = o;
}

// ---------------------------------------------------------------------------
// Build W_cat rows 0..2047 (q,k with hedgehog fold). 16 e-rows per block.
// ---------------------------------------------------------------------------
__global__ void eff_weights2_kernel(const float* __restrict__ Wq, const float* __restrict__ Wk,
                                    const float* __restrict__ fmq_w, const float* __restrict__ fmk_w,
                                    short* __restrict__ Wcat)
{
  __shared__ float fm[16 * 128];
  const int blk = blockIdx.x;
  const int sel = blk >> 6, h = (blk >> 3) & 7, eg = blk & 7;
  const float* W   = sel ? Wk : Wq;
  const float* fmw = sel ? fmk_w : fmq_w;
  const int tid = threadIdx.x;
  const int e0 = eg * 16;
  for (int i = tid; i < 2048; i += 256) fm[i] = fmw[e0 * 128 + i];
  __syncthreads();
  float acc[16][4] = {};
  for (int d = 0; d < 128; d += 4) {
    f32x4 w0 = *(const f32x4*)(W + (size_t)(h * 128 + d + 0) * 1024 + tid * 4);
    f32x4 w1 = *(const f32x4*)(W + (size_t)(h * 128 + d + 1) * 1024 + tid * 4);
    f32x4 w2 = *(const f32x4*)(W + (size_t)(h * 128 + d + 2) * 1024 + tid * 4);
    f32x4 w3 = *(const f32x4*)(W + (size_t)(h * 128 + d + 3) * 1024 + tid * 4);
#pragma unroll
    for (int e = 0; e < 16; ++e) {
      f32x4 fv = *(const f32x4*)&fm[e * 128 + d];
#pragma unroll
      for (int c = 0; c < 4; ++c)
        acc[e][c] += fv[0] * w0[c] + fv[1] * w1[c] + fv[2] * w2[c] + fv[3] * w3[c];
    }
  }
#pragma unroll
  for (int e = 0; e < 16; ++e) {
    sshort4 o;
#pragma unroll
    for (int c = 0; c < 4; ++c) o[c] = f2b(acc[e][c]);
    *(sshort4*)(Wcat + (size_t)(sel * 1024 + h * 128 + e0 + e) * 1024 + tid * 4) = o;
  }
}

// ---------------------------------------------------------------------------
// Tiled bf16 MFMA GEMM, C = A @ B^T.  A[M][K], B[N][K] row-major bf16.
// 128x128 tile, 4 waves, BK=64 ([128][64] tiles, 128B rows) with the
// slot^=(row&7) swizzle (both-sides: pre-swizzled global_load_lds source +
// swizzled ds_read) -> conflict-free b128 reads.
// ---------------------------------------------------------------------------
template<int EPI>
__launch_bounds__(256, 3)
__global__ void gemm_bt(const short* __restrict__ A, const short* __restrict__ B,
                        int K, int N, float* __restrict__ C,
                        const float* __restrict__ qb, const float* __restrict__ kb,
                        short* __restrict__ qf, short* __restrict__ kf,
                        short* __restrict__ kfT, short* __restrict__ vT)
{
  __shared__ __align__(16) char smem[33792];   // 32KB tiles | 33KB epilogue
  short* lds = (short*)smem;
  float* ep  = (float*)smem;

  const int tid = threadIdx.x;
  const int w = tid >> 6, l = tid & 63;
  const int wr = w >> 1, wc = w & 1;

  // XCD-aware bijective block swizzle (nwg % 8 == 0 for both call sites)
  const int nbx = gridDim.x;
  const int orig = blockIdx.y * nbx + blockIdx.x;
  const int cpx = (nbx * gridDim.y) >> 3;
  const int wg = (orig & 7) * cpx + (orig >> 3);
  const int m0 = (wg / nbx) * 128, n0 = (wg % nbx) * 128;

  short* ldsA = lds;
  short* ldsB = lds + 8192;
  const int sr8 = l >> 3;                 // staging row within 8-row segment
  const int sl8 = ((l & 7) ^ sr8) * 8;    // pre-swizzled source slot (shorts)

  f32x4 acc[4][4] = {};

  for (int k0 = 0; k0 < K; k0 += 64) {
    __syncthreads();
#pragma unroll
    for (int j = 0; j < 4; ++j) {
      const int seg = w * 4 + j;
      const int row = seg * 8 + sr8;
      gload16(A + (size_t)(m0 + row) * K + k0 + sl8, ldsA + seg * 512);
      gload16(B + (size_t)(n0 + row) * K + k0 + sl8, ldsB + seg * 512);
    }
    __syncthreads();
#pragma unroll
    for (int kk = 0; kk < 2; ++kk) {
      const int rs = ((kk * 4 + (l >> 4)) ^ (l & 7)) * 8;
      bf16x8 af[4], bfr[4];
#pragma unroll
      for (int m = 0; m < 4; ++m)
        af[m] = ld8(ldsA + (wr * 64 + m * 16 + (l & 15)) * 64 + rs);
#pragma unroll
      for (int n = 0; n < 4; ++n)
        bfr[n] = ld8(ldsB + (wc * 64 + n * 16 + (l & 15)) * 64 + rs);
#pragma unroll
      for (int m = 0; m < 4; ++m)
#pragma unroll
        for (int n = 0; n < 4; ++n)
          acc[m][n] = mfma16(af[m], bfr[n], acc[m][n]);
    }
  }

  // ---------------- epilogue: LDS-staged, coalesced ----------------
  const int seg = (EPI == 1) ? (n0 >> 10) : 0;          // 0=q 1=k 2=v
  const int b   = m0 >> 11, tok0 = m0 & 2047, c0 = tok0 >> 6;
  const int h   = (n0 & 1023) >> 7;
  const int bh  = b * 8 + h;

  for (int half = 0; half < 2; ++half) {
    __syncthreads();
    if (wr == half) {
#pragma unroll
      for (int n = 0; n < 4; ++n) {
        const int cl = wc * 64 + n * 16 + (l & 15);
        float bb = 0.f;
        if constexpr (EPI == 1) bb = (seg == 0) ? qb[cl] : (seg == 1) ? kb[cl] : 0.f;
#pragma unroll
        for (int m = 0; m < 4; ++m)
#pragma unroll
          for (int r = 0; r < 4; ++r) {
            const int rl = m * 16 + (l >> 4) * 4 + r;
            ep[rl * 132 + (cl ^ ((rl & 7) << 2))] = acc[m][n][r] + bb;
          }
      }
    }
    __syncthreads();

    if constexpr (EPI == 0) {
#pragma unroll
      for (int it = 0; it < 8; ++it) {
        const int tl = it * 8 + (tid >> 5);
        const int q = tid & 31;
        f32x4 v4 = *(const f32x4*)&ep[tl * 132 + ((q * 4) ^ ((tl & 7) << 2))];
        *(f32x4*)(C + (size_t)(m0 + half * 64 + tl) * N + n0 + q * 4) = v4;
      }
    } else {
      if (seg <= 1) {
        short* dst = (seg == 0) ? qf : kf;
        const float sc = (seg == 0) ? 0.0625f : 1.0f;
#pragma unroll
        for (int it = 0; it < 8; ++it) {
          const int tl = it * 8 + (tid >> 5);
          const int q = tid & 31;
          f32x4 y4 = *(const f32x4*)&ep[tl * 132 + ((q * 4) ^ ((tl & 7) << 2))];
          sshort4 sp, sm;
#pragma unroll
          for (int j = 0; j < 4; ++j) {
            sp[j] = f2b(__expf(y4[j]) * sc);
            sm[j] = f2b(__expf(-y4[j]) * sc);
          }
          short* rowp = dst + ((size_t)bh * 2048 + tok0 + half * 64 + tl) * 256;
          *(sshort4*)(rowp + q * 4)       = sp;
          *(sshort4*)(rowp + 128 + q * 4) = sm;
        }
        if (seg == 1) {
#pragma unroll
          for (int p2 = 0; p2 < 8; ++p2) {
            const int r = p2 * 32 + (tid >> 3);
            const int e = r & 127, sg = r >> 7;
            const int oct = (tid & 7) * 8;
            short8 o;
#pragma unroll
            for (int i = 0; i < 8; ++i) {
              float y = ep[(oct + i) * 132 + (e ^ (i << 2))];
              o[i] = f2b(__expf(sg ? -y : y));
            }
            *(short8*)(kfT + (((size_t)bh * 32 + c0 + half) * 256 + r) * 64 + oct) = o;
          }
        }
      } else {
#pragma unroll
        for (int p2 = 0; p2 < 4; ++p2) {
          const int r = p2 * 32 + (tid >> 3);
          const int oct = (tid & 7) * 8;
          short8 o;
#pragma unroll
          for (int i = 0; i < 8; ++i)
            o[i] = f2b(ep[(oct + i) * 132 + (r ^ (i << 2))]);
          *(short8*)(vT + (((size_t)bh * 32 + c0 + half) * 128 + r) * 64 + oct) = o;
        }
      }
    }
  }
}

// ---------------------------------------------------------------------------
// Pass A: per (bh,chunk) GT = V^T @ K -> [128 v][256 d] bf16.
// Operands staged in LDS (coalesced gload16, row&7 swizzle).
// ---------------------------------------------------------------------------
__launch_bounds__(256, 3)
__global__ void passA_kernel(const short* __restrict__ kfT, const short* __restrict__ vT,
                             short* __restrict__ GT)
{
  const int bhc = blockIdx.x;                 // bh*32 + c
  const int tid = threadIdx.x, w = tid >> 6, l = tid & 63;
  __shared__ __align__(16) short skT[256 * 64];  // 32KB
  __shared__ __align__(16) short svt[128 * 64];  // 16KB
  const short* kg = kfT + (size_t)bhc * 256 * 64;
  const short* vg = vT  + (size_t)bhc * 128 * 64;
  short* G = GT + (size_t)bhc * 128 * 256;
  const int sr8 = l >> 3, sl8 = ((l & 7) ^ sr8) * 8;

#pragma unroll
  for (int j = 0; j < 8; ++j) {
    const int seg = w * 8 + j;
    gload16(kg + (size_t)(seg * 8 + sr8) * 64 + sl8, skT + seg * 512);
  }
#pragma unroll
  for (int j = 0; j < 4; ++j) {
    const int seg = w * 4 + j;
    gload16(vg + (size_t)(seg * 8 + sr8) * 64 + sl8, svt + seg * 512);
  }
  __syncthreads();

#pragma unroll
  for (int mi = 0; mi < 2; ++mi) {
    const int v0 = w * 32 + mi * 16;
    bf16x8 a[2];
#pragma unroll
    for (int ks = 0; ks < 2; ++ks)
      a[ks] = ld8(svt + (v0 + (l & 15)) * 64 + ((ks * 4 + (l >> 4)) ^ (l & 7)) * 8);
    f32x4 acc[16] = {};
#pragma unroll
    for (int nt = 0; nt < 16; ++nt)
#pragma unroll
      for (int ks = 0; ks < 2; ++ks) {
        bf16x8 b = ld8(skT + (nt * 16 + (l & 15)) * 64 + ((ks * 4 + (l >> 4)) ^ (l & 7)) * 8);
        acc[nt] = mfma16(a[ks], b, acc[nt]);
      }
#pragma unroll
    for (int nt = 0; nt < 16; ++nt)
#pragma unroll
      for (int r = 0; r < 4; ++r)
        G[(v0 + (l >> 4) * 4 + r) * 256 + nt * 16 + (l & 15)] = f2b(acc[nt][r]);
  }
}

// ---------------------------------------------------------------------------
// In-place exclusive prefix over chunks: GT[bh][c] <- sum_{c'<c} GT[bh][c']
// ---------------------------------------------------------------------------
__global__ void prefix_kernel(short* __restrict__ GT) {
  const int bh = blockIdx.x >> 4, slab = blockIdx.x & 15;
  short* base = GT + (size_t)bh * 32 * 32768 + slab * 2048 + threadIdx.x * 8;
  float acc[8] = {};
  short8 g = *(const short8*)base;
  for (int c = 0; c < 32; ++c) {
    short* p = base + (size_t)c * 32768;
    short8 gn = {};
    if (c < 31) gn = *(const short8*)(p + 32768);
    short8 s;
#pragma unroll
    for (int j = 0; j < 8; ++j) s[j] = f2b(acc[j]);
    *(short8*)p = s;
#pragma unroll
    for (int j = 0; j < 8; ++j) acc[j] += b2f(g[j]);
    g = gn;
  }
}

// ---------------------------------------------------------------------------
// Pass C: per (bh,chunk): O = tril(Q K^T) V + Q S, fused RMSNorm.
// q fragments in registers; k / ST / V staged via LDS (two 64-row halves).
// ---------------------------------------------------------------------------
__launch_bounds__(256, 3)
__global__ void passC_kernel(const short* __restrict__ qf, const short* __restrict__ kf,
                             const short* __restrict__ vT, const short* __restrict__ ST,
                             const float* __restrict__ rms_w, short* __restrict__ o_n)
{
  const int bhc = blockIdx.x, bh = bhc >> 5, c = bhc & 31;
  const int tid = threadIdx.x, w = tid >> 6, l = tid & 63;
  __shared__ __align__(16) short bufA[64 * 256];   // 32KB: k-tile, then st halves
  __shared__ __align__(16) short bufV[64 * 64];    // 8KB: vt halves
  __shared__ __align__(16) short attn[64 * 72];    // 9KB
  const short* qg = qf + ((size_t)bh * 2048 + c * 64) * 256;
  const short* kg = kf + ((size_t)bh * 2048 + c * 64) * 256;
  const short* vg = vT + (size_t)bhc * 128 * 64;
  const short* sg = ST + (size_t)bhc * 128 * 256;
  const int r0 = w * 16;
  const int sr8 = l >> 3, sl8 = ((l & 7) ^ sr8) * 8;   // [.][64] tiles
  const int l5 = l >> 5, s32 = l & 31;                 // [.][256] tiles

  // stage k-tile [64][256]
#pragma unroll
  for (int j = 0; j < 8; ++j) {
    const int seg = w * 8 + j;
    const int row = seg * 2 + l5;
    gload16(kg + (size_t)row * 256 + (s32 ^ (row & 7)) * 8, bufA + seg * 512);
  }
  // q fragments to registers (16 rows/wave, L1-resident)
  bf16x8 qreg[8];
#pragma unroll
  for (int ks = 0; ks < 8; ++ks)
    qreg[ks] = ld8(qg + (size_t)(r0 + (l & 15)) * 256 + ks * 32 + (l >> 4) * 8);

  __syncthreads();
  // intra-chunk scores QK^T (K-dim = 256)
  f32x4 s[4] = {};
#pragma unroll
  for (int ks = 0; ks < 8; ++ks) {
    const int rs = ((ks * 4 + (l >> 4)) ^ (l & 7)) * 8;
#pragma unroll
    for (int nt = 0; nt < 4; ++nt)
      s[nt] = mfma16(qreg[ks], ld8(bufA + (nt * 16 + (l & 15)) * 256 + rs), s[nt]);
  }
#pragma unroll
  for (int nt = 0; nt < 4; ++nt)
#pragma unroll
    for (int r = 0; r < 4; ++r) {
      int rr = r0 + (l >> 4) * 4 + r;
      int tt = nt * 16 + (l & 15);
      attn[rr * 72 + tt] = (tt <= rr) ? f2b(s[nt][r]) : (short)0;
    }

  f32x4 o[8] = {};
#pragma unroll
  for (int h = 0; h < 2; ++h) {
    __syncthreads();             // prev bufA/bufV readers done; attn visible
#pragma unroll
    for (int j = 0; j < 8; ++j) {
      const int seg = w * 8 + j;
      const int row = seg * 2 + l5;
      gload16(sg + (size_t)(h * 64 + row) * 256 + (s32 ^ (row & 7)) * 8, bufA + seg * 512);
    }
#pragma unroll
    for (int j = 0; j < 2; ++j) {
      const int seg = w * 2 + j;
      const int row = seg * 8 + sr8;
      gload16(vg + (size_t)(h * 64 + row) * 64 + sl8, bufV + seg * 512);
    }
    __syncthreads();
    // intra: attn @ V-half (K-dim = 64)
#pragma unroll
    for (int ks = 0; ks < 2; ++ks) {
      bf16x8 a = ld8(attn + (r0 + (l & 15)) * 72 + ks * 32 + (l >> 4) * 8);
      const int rs = ((ks * 4 + (l >> 4)) ^ (l & 7)) * 8;
#pragma unroll
      for (int nt = 0; nt < 4; ++nt)
        o[h * 4 + nt] = mfma16(a, ld8(bufV + (nt * 16 + (l & 15)) * 64 + rs), o[h * 4 + nt]);
    }
    // inter: Q @ S-half (K-dim = 256)
#pragma unroll
    for (int ks = 0; ks < 8; ++ks) {
      const int rs = ((ks * 4 + (l >> 4)) ^ (l & 7)) * 8;
#pragma unroll
      for (int nt = 0; nt < 4; ++nt)
        o[h * 4 + nt] = mfma16(qreg[ks], ld8(bufA + (nt * 16 + (l & 15)) * 256 + rs), o[h * 4 + nt]);
    }
  }

  // fused RMSNorm over DV=128 + store bf16
  const int b = bh >> 3, hh = bh & 7;
#pragma unroll
  for (int r = 0; r < 4; ++r) {
    float ss = 0.f;
#pragma unroll
    for (int nt = 0; nt < 8; ++nt) ss += o[nt][r] * o[nt][r];
    ss += __shfl_xor(ss, 1);
    ss += __shfl_xor(ss, 2);
    ss += __shfl_xor(ss, 4);
    ss += __shfl_xor(ss, 8);
    float sc = rsqrtf(ss * (1.0f / 128.0f) + 1e-5f);
    int tok = c * 64 + r0 + (l >> 4) * 4 + r;
    size_t ob = ((size_t)b * 2048 + tok) * 1024 + hh * 128;
#pragma unroll
    for (int nt = 0; nt < 8; ++nt) {
      int vcol = nt * 16 + (l & 15);
      o_n[ob + vcol] = f2b(o[nt][r] * sc * rms_w[vcol]);
    }
  }
}

// ---------------------------------------------------------------------------
extern "C" void kernel_launch(void* const* d_in, const int* in_sizes, int n_in,
                              void* d_out, int out_size, void* d_ws, size_t ws_size,
                              hipStream_t stream)
{
  const float* x     = (const float*)d_in[0];
  const float* Wq    = (const float*)d_in[1];
  const float* Wk    = (const float*)d_in[2];
  const float* Wv    = (const float*)d_in[3];
  const float* Wo    = (const float*)d_in[4];
  const float* fmq_w = (const float*)d_in[5];
  const float* fmq_b = (const float*)d_in[6];
  const float* fmk_w = (const float*)d_in[7];
  const float* fmk_b = (const float*)d_in[8];
  const float* rms_w = (const float*)d_in[9];
  float* out = (float*)d_out;

  char* ws = (char*)d_ws;
  short* x_b  = (short*)(ws);                  // 16.78 MB  (reused as o_norm later)
  short* Wcat = (short*)(ws + 16777216);       //  6.29 MB
  short* Wo_b = (short*)(ws + 23068672);       //  2.10 MB
  short* qf   = (short*)(ws + 25165824);       // 33.55 MB
  short* kf   = (short*)(ws + 58720256);       // 33.55 MB
  short* kfT  = (short*)(ws + 92274688);       // 33.55 MB
  short* vT   = (short*)(ws + 125829120);      // 16.78 MB
  short* GT   = (short*)(ws + 142606336);      // 33.55 MB   (becomes S^T in-place)
  short* o_n  = x_b;                           // alias: x_b dead after QKV GEMM

  convert_kernel<<<4096, 256, 0, stream>>>(x, x_b, 8388608);
  convert_kernel<<<512, 256, 0, stream>>>(Wo, Wo_b, 1048576);
  convert_kernel<<<512, 256, 0, stream>>>(Wv, Wcat + 2097152, 1048576);
  eff_weights2_kernel<<<128, 256, 0, stream>>>(Wq, Wk, fmq_w, fmk_w, Wcat);
  gemm_bt<1><<<dim3(24, 64), 256, 0, stream>>>(x_b, Wcat, 1024, 3072, nullptr,
                                               fmq_b, fmk_b, qf, kf, kfT, vT);
  passA_kernel<<<1024, 256, 0, stream>>>(kfT, vT, GT);
  prefix_kernel<<<512, 256, 0, stream>>>(GT);
  passC_kernel<<<1024, 256, 0, stream>>>(qf, kf, vT, GT, rms_w, o_n);
  gemm_bt<0><<<dim3(8, 64), 256, 0, stream>>>(o_n, Wo_b, 1024, 1024, out,
                                              nullptr, nullptr, nullptr, nullptr,
                                              nullptr, nullptr);
}

// Round 6
// 363.290 us; speedup vs baseline: 1.2860x; 1.0220x over previous
//
#include <hip/hip_runtime.h>
#include <cstdint>
#include <cstddef>

#define DEV __device__ __forceinline__

typedef __attribute__((ext_vector_type(8))) short   short8;
typedef __attribute__((ext_vector_type(4))) short   sshort4;
typedef __attribute__((ext_vector_type(8))) __bf16  bf16x8;
typedef __attribute__((ext_vector_type(4))) float   f32x4;

typedef void as1_void __attribute__((address_space(1)));
typedef void as3_void __attribute__((address_space(3)));

DEV short f2b(float f) {
  unsigned u = __float_as_uint(f);
  unsigned r = (u + 0x7fffu + ((u >> 16) & 1u)) >> 16;
  return (short)r;
}
DEV float b2f(short s) {
  return __uint_as_float(((unsigned)(unsigned short)s) << 16);
}

DEV void gload16(const void* g, void* l) {
  __builtin_amdgcn_global_load_lds((as1_void*)g, (as3_void*)l, 16, 0, 0);
}

DEV bf16x8 ld8(const short* p) { return *reinterpret_cast<const bf16x8*>(p); }

DEV f32x4 mfma16(bf16x8 a, bf16x8 b, f32x4 c) {
  return __builtin_amdgcn_mfma_f32_16x16x32_bf16(a, b, c, 0, 0, 0);
}

// ---------------------------------------------------------------------------
// fp32 -> bf16 convert (vectorized, 8 elems/thread)
// ---------------------------------------------------------------------------
__global__ void convert_kernel(const float* __restrict__ src, short* __restrict__ dst, int n) {
  int i = (blockIdx.x * 256 + threadIdx.x) * 8;
  if (i + 8 > n) return;
  float4 a = *(const float4*)(src + i);
  float4 b = *(const float4*)(src + i + 4);
  short8 o;
  o[0] = f2b(a.x); o[1] = f2b(a.y); o[2] = f2b(a.z); o[3] = f2b(a.w);
  o[4] = f2b(b.x); o[5] = f2b(b.y); o[6] = f2b(b.z); o[7] = f2b(b.w);
  *(short8*)(dst + i) = o;
}

// ---------------------------------------------------------------------------
// Build W_cat rows 0..2047 (q,k with hedgehog fold). 16 e-rows per block.
// ---------------------------------------------------------------------------
__global__ void eff_weights2_kernel(const float* __restrict__ Wq, const float* __restrict__ Wk,
                                    const float* __restrict__ fmq_w, const float* __restrict__ fmk_w,
                                    short* __restrict__ Wcat)
{
  __shared__ float fm[16 * 128];
  const int blk = blockIdx.x;
  const int sel = blk >> 6, h = (blk >> 3) & 7, eg = blk & 7;
  const float* W   = sel ? Wk : Wq;
  const float* fmw = sel ? fmk_w : fmq_w;
  const int tid = threadIdx.x;
  const int e0 = eg * 16;
  for (int i = tid; i < 2048; i += 256) fm[i] = fmw[e0 * 128 + i];
  __syncthreads();
  float acc[16][4] = {};
  for (int d = 0; d < 128; d += 4) {
    f32x4 w0 = *(const f32x4*)(W + (size_t)(h * 128 + d + 0) * 1024 + tid * 4);
    f32x4 w1 = *(const f32x4*)(W + (size_t)(h * 128 + d + 1) * 1024 + tid * 4);
    f32x4 w2 = *(const f32x4*)(W + (size_t)(h * 128 + d + 2) * 1024 + tid * 4);
    f32x4 w3 = *(const f32x4*)(W + (size_t)(h * 128 + d + 3) * 1024 + tid * 4);
#pragma unroll
    for (int e = 0; e < 16; ++e) {
      f32x4 fv = *(const f32x4*)&fm[e * 128 + d];
#pragma unroll
      for (int c = 0; c < 4; ++c)
        acc[e][c] += fv[0] * w0[c] + fv[1] * w1[c] + fv[2] * w2[c] + fv[3] * w3[c];
    }
  }
#pragma unroll
  for (int e = 0; e < 16; ++e) {
    sshort4 o;
#pragma unroll
    for (int c = 0; c < 4; ++c) o[c] = f2b(acc[e][c]);
    *(sshort4*)(Wcat + (size_t)(sel * 1024 + h * 128 + e0 + e) * 1024 + tid * 4) = o;
  }
}

// ---------------------------------------------------------------------------
// 256x256 8-phase bf16 GEMM, C = A @ B^T.  8 waves (512 thr), per-wave C
// 128x64. BK=64, dbuf LDS 128KB. Counted vmcnt(2) at phases 4/8 only.
// Staging schedule race-audited: each half-tile staged >=1 barrier after its
// last reader's lgkmcnt(0) drain.
// EPI=0: fp32 C.  EPI=1: hedgehog features qf/kf (+ transposed kfT, vT).
// ---------------------------------------------------------------------------
template<int EPI>
__launch_bounds__(512, 2)
__global__ void gemm256(const short* __restrict__ A, const short* __restrict__ B,
                        const int K, const int N, float* __restrict__ C,
                        const float* __restrict__ qb, const float* __restrict__ kb,
                        short* __restrict__ qf, short* __restrict__ kf,
                        short* __restrict__ kfT, short* __restrict__ vT)
{
  __shared__ __align__(16) short lds[65536];   // [p][A:16384|B:16384] shorts
  float* ep = (float*)lds;                     // epilogue reuse (67.6 KB)

  const int tid = threadIdx.x;
  const int w = tid >> 6, l = tid & 63;
  const int wr = w >> 2, wc = w & 3;           // 2(M) x 4(N) wave grid

  // XCD-aware bijective block swizzle (nwg % 8 == 0 both call sites)
  const int nbx = gridDim.x;
  const int orig = blockIdx.y * nbx + blockIdx.x;
  const int cpx = (nbx * gridDim.y) >> 3;
  const int wg = (orig & 7) * cpx + (orig >> 3);
  const int m0 = (wg / nbx) * 256, n0 = (wg % nbx) * 256;

  const int srow = tid >> 3;                       // 0..63
  const int scol = ((tid & 7) ^ (srow & 7)) * 8;   // pre-swizzled source slot
  const int wbase = w * 8;

  f32x4 acc[8][4] = {};

  // stage 64 rows [R..R+64) of tile-array (aoff 0=A,16384=B) parity p, K-tile t
  auto STG = [&](const short* src, int g0, int p, int aoff, int R, int t) {
    gload16(src + (size_t)(g0 + R + srow) * K + t * 64 + scol,
            lds + p * 32768 + aoff + (R + wbase) * 64);
  };

  // prologue: K-tiles 0 (buf0) and 1 (buf1) fully staged
#pragma unroll
  for (int R = 0; R < 256; R += 64) {
    STG(A, m0, 0, 0, R, 0);
    STG(B, n0, 0, 16384, R, 0);
    STG(A, m0, 1, 0, R, 1);
    STG(B, n0, 1, 16384, R, 1);
  }
  asm volatile("s_waitcnt vmcnt(0)" ::: "memory");
  __builtin_amdgcn_s_barrier();

#define PHASE(p, q, STAGES, TAIL) { \
    bf16x8 af[4][2], bf[2][2]; \
    _Pragma("unroll") \
    for (int m = 0; m < 4; ++m) { \
      const int r = wr * 128 + ((q) >> 1) * 64 + m * 16 + (l & 15); \
      _Pragma("unroll") \
      for (int kk = 0; kk < 2; ++kk) \
        af[m][kk] = ld8(lds + (p) * 32768 + r * 64 + ((kk * 4 + (l >> 4)) ^ (r & 7)) * 8); \
    } \
    _Pragma("unroll") \
    for (int n = 0; n < 2; ++n) { \
      const int r = wc * 64 + ((q) & 1) * 32 + n * 16 + (l & 15); \
      _Pragma("unroll") \
      for (int kk = 0; kk < 2; ++kk) \
        bf[n][kk] = ld8(lds + (p) * 32768 + 16384 + r * 64 + ((kk * 4 + (l >> 4)) ^ (r & 7)) * 8); \
    } \
    STAGES; \
    __builtin_amdgcn_s_barrier(); \
    asm volatile("s_waitcnt lgkmcnt(0)" ::: "memory"); \
    __builtin_amdgcn_sched_barrier(0); \
    __builtin_amdgcn_s_setprio(1); \
    _Pragma("unroll") \
    for (int m = 0; m < 4; ++m) \
      _Pragma("unroll") \
      for (int n = 0; n < 2; ++n) \
        _Pragma("unroll") \
        for (int kk = 0; kk < 2; ++kk) \
          acc[((q) >> 1) * 4 + m][((q) & 1) * 2 + n] = \
            mfma16(af[m][kk], bf[n][kk], acc[((q) >> 1) * 4 + m][((q) & 1) * 2 + n]); \
    __builtin_amdgcn_s_setprio(0); \
    TAIL; \
    __builtin_amdgcn_s_barrier(); \
  }

  const int NI = K >> 7;                       // 2 K-tiles per iteration
  for (int i = 0; i < NI; ++i) {
    const int t1 = 2 * i + 1, t2 = 2 * i + 2, t3 = 2 * i + 3;
    const bool sE = (i < NI - 1), sL = (i > 0);
    // phases 1-4: compute K-tile 2i (buf0)
    PHASE(0, 0, {
      if (sL) { STG(A, m0, 1, 0, 64, t1); STG(A, m0, 1, 0, 192, t1);
                STG(B, n0, 1, 16384, 0, t1); STG(B, n0, 1, 16384, 64, t1); } }, {});
    PHASE(0, 1, {
      if (sL) { STG(B, n0, 1, 16384, 128, t1); STG(B, n0, 1, 16384, 192, t1); } }, {});
    PHASE(0, 2, {
      if (sE) { STG(A, m0, 0, 0, 0, t2); STG(A, m0, 0, 0, 128, t2); } }, {});
    PHASE(0, 3, {}, {
      if (i == NI - 1) { asm volatile("s_waitcnt vmcnt(0)" ::: "memory"); }
      else             { asm volatile("s_waitcnt vmcnt(2)" ::: "memory"); } });
    // phases 5-8: compute K-tile 2i+1 (buf1)
    PHASE(1, 0, {
      if (sE) { STG(A, m0, 0, 0, 64, t2); STG(A, m0, 0, 0, 192, t2); } }, {});
    PHASE(1, 1, {
      if (sE) { STG(B, n0, 0, 16384, 0, t2); STG(B, n0, 0, 16384, 64, t2); } }, {});
    PHASE(1, 2, {
      if (sE) { STG(B, n0, 0, 16384, 128, t2); STG(B, n0, 0, 16384, 192, t2); } }, {});
    PHASE(1, 3, {
      if (sE) { STG(A, m0, 1, 0, 0, t3); STG(A, m0, 1, 0, 128, t3); } }, {
      asm volatile("s_waitcnt vmcnt(2)" ::: "memory"); });
  }
#undef PHASE

  // ---------------- epilogue: LDS-staged (f32 [64][264], XOR cols) ----------
  const int seg = (EPI == 1) ? (n0 >> 10) : 0;         // 0=q 1=k 2=v
  const int b = m0 >> 11, tok0 = m0 & 2047, c0 = tok0 >> 6;
  const int hbase = (n0 & 1023) >> 7;
  const int bh0 = b * 8 + hbase;

#pragma unroll
  for (int h = 0; h < 4; ++h) {
    __syncthreads();
    if (wr == (h >> 1)) {
      const int mbase = (h & 1) * 4;
#pragma unroll
      for (int n = 0; n < 4; ++n) {
        const int cl = wc * 64 + n * 16 + (l & 15);
        float bb = 0.f;
        if constexpr (EPI == 1) bb = (seg == 0) ? qb[cl & 127] : (seg == 1) ? kb[cl & 127] : 0.f;
#pragma unroll
        for (int m4 = 0; m4 < 4; ++m4)
#pragma unroll
          for (int r = 0; r < 4; ++r) {
            const int rl = m4 * 16 + (l >> 4) * 4 + r;
            ep[rl * 264 + (cl ^ ((rl & 3) << 2))] = acc[mbase + m4][n][r] + bb;
          }
      }
    }
    __syncthreads();

    if constexpr (EPI == 0) {
#pragma unroll
      for (int it = 0; it < 8; ++it) {
        const int tl = it * 8 + (tid >> 6);
        const int cc4 = (tid & 63) * 4;
        f32x4 v4 = *(const f32x4*)&ep[tl * 264 + (cc4 ^ ((tl & 3) << 2))];
        *(f32x4*)(C + (size_t)(m0 + h * 64 + tl) * N + n0 + cc4) = v4;
      }
    } else {
      const int cc = c0 + h;
      if (seg <= 1) {
        short* dst = (seg == 0) ? qf : kf;
        const float sc = (seg == 0) ? 0.0625f : 1.0f;
#pragma unroll
        for (int it = 0; it < 8; ++it) {
          const int tl = it * 8 + (tid >> 6);
          const int cc4 = (tid & 63) * 4;
          f32x4 y4 = *(const f32x4*)&ep[tl * 264 + (cc4 ^ ((tl & 3) << 2))];
          sshort4 sp, sm;
#pragma unroll
          for (int j = 0; j < 4; ++j) {
            sp[j] = f2b(__expf(y4[j]) * sc);
            sm[j] = f2b(__expf(-y4[j]) * sc);
          }
          const int hh = cc4 >> 7, e = cc4 & 127;
          short* rowp = dst + ((size_t)(bh0 + hh) * 2048 + tok0 + h * 64 + tl) * 256;
          *(sshort4*)(rowp + e)       = sp;
          *(sshort4*)(rowp + 128 + e) = sm;
        }
        if (seg == 1) {
#pragma unroll
          for (int p2 = 0; p2 < 8; ++p2) {
            const int idx = p2 * 512 + tid;
            const int er = idx >> 3, oct = (idx & 7) * 8;
            const int hh = er >> 8, rr = er & 255, e = rr & 127, sg = rr >> 7;
            const int cgc = hh * 128 + e;
            short8 o;
#pragma unroll
            for (int ii = 0; ii < 8; ++ii) {
              float y = ep[(oct + ii) * 264 + (cgc ^ (((oct + ii) & 3) << 2))];
              o[ii] = f2b(__expf(sg ? -y : y));
            }
            *(short8*)(kfT + ((size_t)(bh0 + hh) * 32 + cc) * 16384 + (size_t)rr * 64 + oct) = o;
          }
        }
      } else {
#pragma unroll
        for (int p2 = 0; p2 < 4; ++p2) {
          const int idx = p2 * 512 + tid;
          const int er = idx >> 3, oct = (idx & 7) * 8;
          const int hh = er >> 7, vv = er & 127;
          short8 o;
#pragma unroll
          for (int ii = 0; ii < 8; ++ii)
            o[ii] = f2b(ep[(oct + ii) * 264 + (er ^ (((oct + ii) & 3) << 2))]);
          *(short8*)(vT + ((size_t)(bh0 + hh) * 32 + cc) * 8192 + (size_t)vv * 64 + oct) = o;
        }
      }
    }
  }
}

// ---------------------------------------------------------------------------
// Pass A: per (bh,chunk) GT = V^T @ K -> [128 v][256 d] bf16 (LDS-staged)
// ---------------------------------------------------------------------------
__launch_bounds__(256, 3)
__global__ void passA_kernel(const short* __restrict__ kfT, const short* __restrict__ vT,
                             short* __restrict__ GT)
{
  const int bhc = blockIdx.x;
  const int tid = threadIdx.x, w = tid >> 6, l = tid & 63;
  __shared__ __align__(16) short skT[256 * 64];
  __shared__ __align__(16) short svt[128 * 64];
  const short* kg = kfT + (size_t)bhc * 256 * 64;
  const short* vg = vT  + (size_t)bhc * 128 * 64;
  short* G = GT + (size_t)bhc * 128 * 256;
  const int sr8 = l >> 3, sl8 = ((l & 7) ^ sr8) * 8;

#pragma unroll
  for (int j = 0; j < 8; ++j) {
    const int seg = w * 8 + j;
    gload16(kg + (size_t)(seg * 8 + sr8) * 64 + sl8, skT + seg * 512);
  }
#pragma unroll
  for (int j = 0; j < 4; ++j) {
    const int seg = w * 4 + j;
    gload16(vg + (size_t)(seg * 8 + sr8) * 64 + sl8, svt + seg * 512);
  }
  __syncthreads();

#pragma unroll
  for (int mi = 0; mi < 2; ++mi) {
    const int v0 = w * 32 + mi * 16;
    bf16x8 a[2];
#pragma unroll
    for (int ks = 0; ks < 2; ++ks)
      a[ks] = ld8(svt + (v0 + (l & 15)) * 64 + ((ks * 4 + (l >> 4)) ^ (l & 7)) * 8);
    f32x4 acc[16] = {};
#pragma unroll
    for (int nt = 0; nt < 16; ++nt)
#pragma unroll
      for (int ks = 0; ks < 2; ++ks) {
        bf16x8 b = ld8(skT + (nt * 16 + (l & 15)) * 64 + ((ks * 4 + (l >> 4)) ^ (l & 7)) * 8);
        acc[nt] = mfma16(a[ks], b, acc[nt]);
      }
#pragma unroll
    for (int nt = 0; nt < 16; ++nt)
#pragma unroll
      for (int r = 0; r < 4; ++r)
        G[(v0 + (l >> 4) * 4 + r) * 256 + nt * 16 + (l & 15)] = f2b(acc[nt][r]);
  }
}

// ---------------------------------------------------------------------------
// In-place exclusive prefix over chunks
// ---------------------------------------------------------------------------
__global__ void prefix_kernel(short* __restrict__ GT) {
  const int bh = blockIdx.x >> 4, slab = blockIdx.x & 15;
  short* base = GT + (size_t)bh * 32 * 32768 + slab * 2048 + threadIdx.x * 8;
  float acc[8] = {};
  short8 g = *(const short8*)base;
  for (int c = 0; c < 32; ++c) {
    short* p = base + (size_t)c * 32768;
    short8 gn = {};
    if (c < 31) gn = *(const short8*)(p + 32768);
    short8 s;
#pragma unroll
    for (int j = 0; j < 8; ++j) s[j] = f2b(acc[j]);
    *(short8*)p = s;
#pragma unroll
    for (int j = 0; j < 8; ++j) acc[j] += b2f(g[j]);
    g = gn;
  }
}

// ---------------------------------------------------------------------------
// Pass C: per (bh,chunk): O = tril(Q K^T) V + Q S, fused RMSNorm.
// ---------------------------------------------------------------------------
__launch_bounds__(256, 3)
__global__ void passC_kernel(const short* __restrict__ qf, const short* __restrict__ kf,
                             const short* __restrict__ vT, const short* __restrict__ ST,
                             const float* __restrict__ rms_w, short* __restrict__ o_n)
{
  const int bhc = blockIdx.x, bh = bhc >> 5, c = bhc & 31;
  const int tid = threadIdx.x, w = tid >> 6, l = tid & 63;
  __shared__ __align__(16) short bufA[64 * 256];
  __shared__ __align__(16) short bufV[64 * 64];
  __shared__ __align__(16) short attn[64 * 72];
  const short* qg = qf + ((size_t)bh * 2048 + c * 64) * 256;
  const short* kg = kf + ((size_t)bh * 2048 + c * 64) * 256;
  const short* vg = vT + (size_t)bhc * 128 * 64;
  const short* sg = ST + (size_t)bhc * 128 * 256;
  const int r0 = w * 16;
  const int sr8 = l >> 3, sl8 = ((l & 7) ^ sr8) * 8;
  const int l5 = l >> 5, s32 = l & 31;

#pragma unroll
  for (int j = 0; j < 8; ++j) {
    const int seg = w * 8 + j;
    const int row = seg * 2 + l5;
    gload16(kg + (size_t)row * 256 + (s32 ^ (row & 7)) * 8, bufA + seg * 512);
  }
  bf16x8 qreg[8];
#pragma unroll
  for (int ks = 0; ks < 8; ++ks)
    qreg[ks] = ld8(qg + (size_t)(r0 + (l & 15)) * 256 + ks * 32 + (l >> 4) * 8);

  __syncthreads();
  f32x4 s[4] = {};
#pragma unroll
  for (int ks = 0; ks < 8; ++ks) {
    const int rs = ((ks * 4 + (l >> 4)) ^ (l & 7)) * 8;
#pragma unroll
    for (int nt = 0; nt < 4; ++nt)
      s[nt] = mfma16(qreg[ks], ld8(bufA + (nt * 16 + (l & 15)) * 256 + rs), s[nt]);
  }
#pragma unroll
  for (int nt = 0; nt < 4; ++nt)
#pragma unroll
    for (int r = 0; r < 4; ++r) {
      int rr = r0 + (l >> 4) * 4 + r;
      int tt = nt * 16 + (l & 15);
      attn[rr * 72 + tt] = (tt <= rr) ? f2b(s[nt][r]) : (short)0;
    }

  f32x4 o[8] = {};
#pragma unroll
  for (int h = 0; h < 2; ++h) {
    __syncthreads();
#pragma unroll
    for (int j = 0; j < 8; ++j) {
      const int seg = w * 8 + j;
      const int row = seg * 2 + l5;
      gload16(sg + (size_t)(h * 64 + row) * 256 + (s32 ^ (row & 7)) * 8, bufA + seg * 512);
    }
#pragma unroll
    for (int j = 0; j < 2; ++j) {
      const int seg = w * 2 + j;
      const int row = seg * 8 + sr8;
      gload16(vg + (size_t)(h * 64 + row) * 64 + sl8, bufV + seg * 512);
    }
    __syncthreads();
#pragma unroll
    for (int ks = 0; ks < 2; ++ks) {
      bf16x8 a = ld8(attn + (r0 + (l & 15)) * 72 + ks * 32 + (l >> 4) * 8);
      const int rs = ((ks * 4 + (l >> 4)) ^ (l & 7)) * 8;
#pragma unroll
      for (int nt = 0; nt < 4; ++nt)
        o[h * 4 + nt] = mfma16(a, ld8(bufV + (nt * 16 + (l & 15)) * 64 + rs), o[h * 4 + nt]);
    }
#pragma unroll
    for (int ks = 0; ks < 8; ++ks) {
      const int rs = ((ks * 4 + (l >> 4)) ^ (l & 7)) * 8;
#pragma unroll
      for (int nt = 0; nt < 4; ++nt)
        o[h * 4 + nt] = mfma16(qreg[ks], ld8(bufA + (nt * 16 + (l & 15)) * 256 + rs), o[h * 4 + nt]);
    }
  }

  const int b = bh >> 3, hh = bh & 7;
#pragma unroll
  for (int r = 0; r < 4; ++r) {
    float ss = 0.f;
#pragma unroll
    for (int nt = 0; nt < 8; ++nt) ss += o[nt][r] * o[nt][r];
    ss += __shfl_xor(ss, 1);
    ss += __shfl_xor(ss, 2);
    ss += __shfl_xor(ss, 4);
    ss += __shfl_xor(ss, 8);
    float sc = rsqrtf(ss * (1.0f / 128.0f) + 1e-5f);
    int tok = c * 64 + r0 + (l >> 4) * 4 + r;
    size_t ob = ((size_t)b * 2048 + tok) * 1024 + hh * 128;
#pragma unroll
    for (int nt = 0; nt < 8; ++nt) {
      int vcol = nt * 16 + (l & 15);
      o_n[ob + vcol] = f2b(o[nt][r] * sc * rms_w[vcol]);
    }
  }
}

// ---------------------------------------------------------------------------
extern "C" void kernel_launch(void* const* d_in, const int* in_sizes, int n_in,
                              void* d_out, int out_size, void* d_ws, size_t ws_size,
                              hipStream_t stream)
{
  const float* x     = (const float*)d_in[0];
  const float* Wq    = (const float*)d_in[1];
  const float* Wk    = (const float*)d_in[2];
  const float* Wv    = (const float*)d_in[3];
  const float* Wo    = (const float*)d_in[4];
  const float* fmq_w = (const float*)d_in[5];
  const float* fmq_b = (const float*)d_in[6];
  const float* fmk_w = (const float*)d_in[7];
  const float* fmk_b = (const float*)d_in[8];
  const float* rms_w = (const float*)d_in[9];
  float* out = (float*)d_out;

  char* ws = (char*)d_ws;
  short* x_b  = (short*)(ws);                  // 16.78 MB  (reused as o_norm later)
  short* Wcat = (short*)(ws + 16777216);       //  6.29 MB
  short* Wo_b = (short*)(ws + 23068672);       //  2.10 MB
  short* qf   = (short*)(ws + 25165824);       // 33.55 MB
  short* kf   = (short*)(ws + 58720256);       // 33.55 MB
  short* kfT  = (short*)(ws + 92274688);       // 33.55 MB
  short* vT   = (short*)(ws + 125829120);      // 16.78 MB
  short* GT   = (short*)(ws + 142606336);      // 33.55 MB   (becomes S^T in-place)
  short* o_n  = x_b;                           // alias: x_b dead after QKV GEMM

  convert_kernel<<<4096, 256, 0, stream>>>(x, x_b, 8388608);
  convert_kernel<<<512, 256, 0, stream>>>(Wo, Wo_b, 1048576);
  convert_kernel<<<512, 256, 0, stream>>>(Wv, Wcat + 2097152, 1048576);
  eff_weights2_kernel<<<128, 256, 0, stream>>>(Wq, Wk, fmq_w, fmk_w, Wcat);
  gemm256<1><<<dim3(12, 32), 512, 0, stream>>>(x_b, Wcat, 1024, 3072, nullptr,
                                               fmq_b, fmk_b, qf, kf, kfT, vT);
  passA_kernel<<<1024, 256, 0, stream>>>(kfT, vT, GT);
  prefix_kernel<<<512, 256, 0, stream>>>(GT);
  passC_kernel<<<1024, 256, 0, stream>>>(qf, kf, vT, GT, rms_w, o_n);
  gemm256<0><<<dim3(4, 32), 512, 0, stream>>>(o_n, Wo_b, 1024, 1024, out,
                                              nullptr, nullptr, nullptr, nullptr,
                                              nullptr, nullptr);
}

// Round 7
// 355.296 us; speedup vs baseline: 1.3149x; 1.0225x over previous
//
#include <hip/hip_runtime.h>
#include <cstdint>
#include <cstddef>

#define DEV __device__ __forceinline__

typedef __attribute__((ext_vector_type(8))) short   short8;
typedef __attribute__((ext_vector_type(4))) short   sshort4;
typedef __attribute__((ext_vector_type(8))) __bf16  bf16x8;
typedef __attribute__((ext_vector_type(4))) float   f32x4;

typedef void as1_void __attribute__((address_space(1)));
typedef void as3_void __attribute__((address_space(3)));

DEV short f2b(float f) {
  unsigned u = __float_as_uint(f);
  unsigned r = (u + 0x7fffu + ((u >> 16) & 1u)) >> 16;
  return (short)r;
}
DEV float b2f(short s) {
  return __uint_as_float(((unsigned)(unsigned short)s) << 16);
}

DEV void gload16(const void* g, void* l) {
  __builtin_amdgcn_global_load_lds((as1_void*)g, (as3_void*)l, 16, 0, 0);
}

DEV bf16x8 ld8(const short* p) { return *reinterpret_cast<const bf16x8*>(p); }

DEV f32x4 mfma16(bf16x8 a, bf16x8 b, f32x4 c) {
  return __builtin_amdgcn_mfma_f32_16x16x32_bf16(a, b, c, 0, 0, 0);
}

// ---------------------------------------------------------------------------
// Fused prep: x->bf16, Wo->bf16, Wv->bf16 (into Wcat rows 2048+), and
// eff_weights (hedgehog fold) for Wcat rows 0..2047. One dispatch.
// grid = 4096 + 512 + 512 + 128 = 5248 blocks.
// ---------------------------------------------------------------------------
__global__ void prep_kernel(const float* __restrict__ x, const float* __restrict__ Wo,
                            const float* __restrict__ Wq, const float* __restrict__ Wk,
                            const float* __restrict__ Wv,
                            const float* __restrict__ fmq_w, const float* __restrict__ fmk_w,
                            short* __restrict__ x_b, short* __restrict__ Wo_b,
                            short* __restrict__ Wcat)
{
  const int blk = blockIdx.x;
  const int tid = threadIdx.x;
  if (blk < 5120) {
    // plain converts
    const float* src;
    short* dst;
    int i;
    if (blk < 4096)      { src = x;  dst = x_b;            i = (blk * 256 + tid) * 8; }
    else if (blk < 4608) { src = Wo; dst = Wo_b;           i = ((blk - 4096) * 256 + tid) * 8; }
    else                 { src = Wv; dst = Wcat + 2097152; i = ((blk - 4608) * 256 + tid) * 8; }
    float4 a = *(const float4*)(src + i);
    float4 b = *(const float4*)(src + i + 4);
    short8 o;
    o[0] = f2b(a.x); o[1] = f2b(a.y); o[2] = f2b(a.z); o[3] = f2b(a.w);
    o[4] = f2b(b.x); o[5] = f2b(b.y); o[6] = f2b(b.z); o[7] = f2b(b.w);
    *(short8*)(dst + i) = o;
  } else {
    // eff_weights: 128 blocks (2 sel x 8 h x 8 eg), 16 e-rows per block
    __shared__ float fm[16 * 128];
    const int eb = blk - 5120;
    const int sel = eb >> 6, h = (eb >> 3) & 7, eg = eb & 7;
    const float* W   = sel ? Wk : Wq;
    const float* fmw = sel ? fmk_w : fmq_w;
    const int e0 = eg * 16;
    for (int i = tid; i < 2048; i += 256) fm[i] = fmw[e0 * 128 + i];
    __syncthreads();
    float acc[16][4] = {};
    for (int d = 0; d < 128; d += 4) {
      f32x4 w0 = *(const f32x4*)(W + (size_t)(h * 128 + d + 0) * 1024 + tid * 4);
      f32x4 w1 = *(const f32x4*)(W + (size_t)(h * 128 + d + 1) * 1024 + tid * 4);
      f32x4 w2 = *(const f32x4*)(W + (size_t)(h * 128 + d + 2) * 1024 + tid * 4);
      f32x4 w3 = *(const f32x4*)(W + (size_t)(h * 128 + d + 3) * 1024 + tid * 4);
#pragma unroll
      for (int e = 0; e < 16; ++e) {
        f32x4 fv = *(const f32x4*)&fm[e * 128 + d];
#pragma unroll
        for (int c = 0; c < 4; ++c)
          acc[e][c] += fv[0] * w0[c] + fv[1] * w1[c] + fv[2] * w2[c] + fv[3] * w3[c];
      }
    }
#pragma unroll
    for (int e = 0; e < 16; ++e) {
      sshort4 o;
#pragma unroll
      for (int c = 0; c < 4; ++c) o[c] = f2b(acc[e][c]);
      *(sshort4*)(Wcat + (size_t)(sel * 1024 + h * 128 + e0 + e) * 1024 + tid * 4) = o;
    }
  }
}

// ---------------------------------------------------------------------------
// 256x256 8-phase bf16 GEMM, C = A @ B^T.  8 waves (512 thr), per-wave C
// 128x64. BK=64, dbuf LDS 128KB. Counted vmcnt(2) at phases 4/8 only.
// Register-held fragments: A-half reused across 2 phases, both B halves
// kept live -> 24 ds_read_b128 per wave per K-tile (the distinct-fragment
// minimum), vs 48 when re-read every phase.
// EPI=0: fp32 C.  EPI=1: hedgehog features qf/kf (+ transposed kfT, vT).
// ---------------------------------------------------------------------------
template<int EPI>
__launch_bounds__(512, 2)
__global__ void gemm256(const short* __restrict__ A, const short* __restrict__ B,
                        const int K, const int N, float* __restrict__ C,
                        const float* __restrict__ qb, const float* __restrict__ kb,
                        short* __restrict__ qf, short* __restrict__ kf,
                        short* __restrict__ kfT, short* __restrict__ vT)
{
  __shared__ __align__(16) short lds[65536];   // [p][A:16384|B:16384] shorts
  float* ep = (float*)lds;                     // epilogue reuse (67.6 KB)

  const int tid = threadIdx.x;
  const int w = tid >> 6, l = tid & 63;
  const int wr = w >> 2, wc = w & 3;           // 2(M) x 4(N) wave grid

  // XCD-aware bijective block swizzle (nwg % 8 == 0 both call sites)
  const int nbx = gridDim.x;
  const int orig = blockIdx.y * nbx + blockIdx.x;
  const int cpx = (nbx * gridDim.y) >> 3;
  const int wg = (orig & 7) * cpx + (orig >> 3);
  const int m0 = (wg / nbx) * 256, n0 = (wg % nbx) * 256;

  const int srow = tid >> 3;                       // 0..63
  const int scol = ((tid & 7) ^ (srow & 7)) * 8;   // pre-swizzled source slot
  const int wbase = w * 8;

  f32x4 acc[8][4] = {};
  bf16x8 af[4][2];        // current A-half fragments (reused across 2 phases)
  bf16x8 bg[2][2][2];     // both B halves kept live

  // stage 64 rows [R..R+64) of tile-array (aoff 0=A,16384=B) parity p, K-tile t
  auto STG = [&](const short* src, int g0, int p, int aoff, int R, int t) {
    gload16(src + (size_t)(g0 + R + srow) * K + t * 64 + scol,
            lds + p * 32768 + aoff + (R + wbase) * 64);
  };

  // prologue: K-tiles 0 (buf0) and 1 (buf1) fully staged
#pragma unroll
  for (int R = 0; R < 256; R += 64) {
    STG(A, m0, 0, 0, R, 0);
    STG(B, n0, 0, 16384, R, 0);
    STG(A, m0, 1, 0, R, 1);
    STG(B, n0, 1, 16384, R, 1);
  }
  asm volatile("s_waitcnt vmcnt(0)" ::: "memory");
  __builtin_amdgcn_s_barrier();

#define PHASE(p, q, DOLDA, DOLDB, STAGES, TAIL) { \
    if (DOLDA) { \
      _Pragma("unroll") \
      for (int m = 0; m < 4; ++m) { \
        const int r = wr * 128 + ((q) >> 1) * 64 + m * 16 + (l & 15); \
        _Pragma("unroll") \
        for (int kk = 0; kk < 2; ++kk) \
          af[m][kk] = ld8(lds + (p) * 32768 + r * 64 + ((kk * 4 + (l >> 4)) ^ (r & 7)) * 8); \
      } \
    } \
    if (DOLDB) { \
      _Pragma("unroll") \
      for (int n = 0; n < 2; ++n) { \
        const int r = wc * 64 + ((q) & 1) * 32 + n * 16 + (l & 15); \
        _Pragma("unroll") \
        for (int kk = 0; kk < 2; ++kk) \
          bg[(q) & 1][n][kk] = ld8(lds + (p) * 32768 + 16384 + r * 64 + ((kk * 4 + (l >> 4)) ^ (r & 7)) * 8); \
      } \
    } \
    STAGES; \
    __builtin_amdgcn_s_barrier(); \
    asm volatile("s_waitcnt lgkmcnt(0)" ::: "memory"); \
    __builtin_amdgcn_sched_barrier(0); \
    __builtin_amdgcn_s_setprio(1); \
    _Pragma("unroll") \
    for (int m = 0; m < 4; ++m) \
      _Pragma("unroll") \
      for (int n = 0; n < 2; ++n) \
        _Pragma("unroll") \
        for (int kk = 0; kk < 2; ++kk) \
          acc[((q) >> 1) * 4 + m][((q) & 1) * 2 + n] = \
            mfma16(af[m][kk], bg[(q) & 1][n][kk], acc[((q) >> 1) * 4 + m][((q) & 1) * 2 + n]); \
    __builtin_amdgcn_s_setprio(0); \
    TAIL; \
    __builtin_amdgcn_s_barrier(); \
  }

  const int NI = K >> 7;                       // 2 K-tiles per iteration
  for (int i = 0; i < NI; ++i) {
    const int t1 = 2 * i + 1, t2 = 2 * i + 2, t3 = 2 * i + 3;
    const bool sE = (i < NI - 1), sL = (i > 0);
    // phases 1-4: compute K-tile 2i (buf0)
    PHASE(0, 0, 1, 1, {
      if (sL) { STG(A, m0, 1, 0, 64, t1); STG(A, m0, 1, 0, 192, t1);
                STG(B, n0, 1, 16384, 0, t1); STG(B, n0, 1, 16384, 64, t1); } }, {});
    PHASE(0, 1, 0, 1, {
      if (sL) { STG(B, n0, 1, 16384, 128, t1); STG(B, n0, 1, 16384, 192, t1); } }, {});
    PHASE(0, 2, 1, 0, {
      if (sE) { STG(A, m0, 0, 0, 0, t2); STG(A, m0, 0, 0, 128, t2); } }, {});
    PHASE(0, 3, 0, 0, {}, {
      if (i == NI - 1) { asm volatile("s_waitcnt vmcnt(0)" ::: "memory"); }
      else             { asm volatile("s_waitcnt vmcnt(2)" ::: "memory"); } });
    // phases 5-8: compute K-tile 2i+1 (buf1)
    PHASE(1, 0, 1, 1, {
      if (sE) { STG(A, m0, 0, 0, 64, t2); STG(A, m0, 0, 0, 192, t2); } }, {});
    PHASE(1, 1, 0, 1, {
      if (sE) { STG(B, n0, 0, 16384, 0, t2); STG(B, n0, 0, 16384, 64, t2); } }, {});
    PHASE(1, 2, 1, 0, {
      if (sE) { STG(B, n0, 0, 16384, 128, t2); STG(B, n0, 0, 16384, 192, t2); } }, {});
    PHASE(1, 3, 0, 0, {
      if (sE) { STG(A, m0, 1, 0, 0, t3); STG(A, m0, 1, 0, 128, t3); } }, {
      asm volatile("s_waitcnt vmcnt(2)" ::: "memory"); });
  }
#undef PHASE

  // ---------------- epilogue: LDS-staged (f32 [64][264], XOR cols) ----------
  const int seg = (EPI == 1) ? (n0 >> 10) : 0;         // 0=q 1=k 2=v
  const int b = m0 >> 11, tok0 = m0 & 2047, c0 = tok0 >> 6;
  const int hbase = (n0 & 1023) >> 7;
  const int bh0 = b * 8 + hbase;

#pragma unroll
  for (int h = 0; h < 4; ++h) {
    __syncthreads();
    if (wr == (h >> 1)) {
      const int mbase = (h & 1) * 4;
#pragma unroll
      for (int n = 0; n < 4; ++n) {
        const int cl = wc * 64 + n * 16 + (l & 15);
        float bb = 0.f;
        if constexpr (EPI == 1) bb = (seg == 0) ? qb[cl & 127] : (seg == 1) ? kb[cl & 127] : 0.f;
#pragma unroll
        for (int m4 = 0; m4 < 4; ++m4)
#pragma unroll
          for (int r = 0; r < 4; ++r) {
            const int rl = m4 * 16 + (l >> 4) * 4 + r;
            ep[rl * 264 + (cl ^ ((rl & 3) << 2))] = acc[mbase + m4][n][r] + bb;
          }
      }
    }
    __syncthreads();

    if constexpr (EPI == 0) {
#pragma unroll
      for (int it = 0; it < 8; ++it) {
        const int tl = it * 8 + (tid >> 6);
        const int cc4 = (tid & 63) * 4;
        f32x4 v4 = *(const f32x4*)&ep[tl * 264 + (cc4 ^ ((tl & 3) << 2))];
        *(f32x4*)(C + (size_t)(m0 + h * 64 + tl) * N + n0 + cc4) = v4;
      }
    } else {
      const int cc = c0 + h;
      if (seg <= 1) {
        short* dst = (seg == 0) ? qf : kf;
        const float sc = (seg == 0) ? 0.0625f : 1.0f;
#pragma unroll
        for (int it = 0; it < 8; ++it) {
          const int tl = it * 8 + (tid >> 6);
          const int cc4 = (tid & 63) * 4;
          f32x4 y4 = *(const f32x4*)&ep[tl * 264 + (cc4 ^ ((tl & 3) << 2))];
          sshort4 sp, sm;
#pragma unroll
          for (int j = 0; j < 4; ++j) {
            sp[j] = f2b(__expf(y4[j]) * sc);
            sm[j] = f2b(__expf(-y4[j]) * sc);
          }
          const int hh = cc4 >> 7, e = cc4 & 127;
          short* rowp = dst + ((size_t)(bh0 + hh) * 2048 + tok0 + h * 64 + tl) * 256;
          *(sshort4*)(rowp + e)       = sp;
          *(sshort4*)(rowp + 128 + e) = sm;
        }
        if (seg == 1) {
#pragma unroll
          for (int p2 = 0; p2 < 8; ++p2) {
            const int idx = p2 * 512 + tid;
            const int er = idx >> 3, oct = (idx & 7) * 8;
            const int hh = er >> 8, rr = er & 255, e = rr & 127, sg = rr >> 7;
            const int cgc = hh * 128 + e;
            short8 o;
#pragma unroll
            for (int ii = 0; ii < 8; ++ii) {
              float y = ep[(oct + ii) * 264 + (cgc ^ (((oct + ii) & 3) << 2))];
              o[ii] = f2b(__expf(sg ? -y : y));
            }
            *(short8*)(kfT + ((size_t)(bh0 + hh) * 32 + cc) * 16384 + (size_t)rr * 64 + oct) = o;
          }
        }
      } else {
#pragma unroll
        for (int p2 = 0; p2 < 4; ++p2) {
          const int idx = p2 * 512 + tid;
          const int er = idx >> 3, oct = (idx & 7) * 8;
          const int hh = er >> 7, vv = er & 127;
          short8 o;
#pragma unroll
          for (int ii = 0; ii < 8; ++ii)
            o[ii] = f2b(ep[(oct + ii) * 264 + (er ^ (((oct + ii) & 3) << 2))]);
          *(short8*)(vT + ((size_t)(bh0 + hh) * 32 + cc) * 8192 + (size_t)vv * 64 + oct) = o;
        }
      }
    }
  }
}

// ---------------------------------------------------------------------------
// Pass A: per (bh,chunk) GT = V^T @ K -> [128 v][256 d] bf16 (LDS-staged)
// ---------------------------------------------------------------------------
__launch_bounds__(256, 3)
__global__ void passA_kernel(const short* __restrict__ kfT, const short* __restrict__ vT,
                             short* __restrict__ GT)
{
  const int bhc = blockIdx.x;
  const int tid = threadIdx.x, w = tid >> 6, l = tid & 63;
  __shared__ __align__(16) short skT[256 * 64];
  __shared__ __align__(16) short svt[128 * 64];
  const short* kg = kfT + (size_t)bhc * 256 * 64;
  const short* vg = vT  + (size_t)bhc * 128 * 64;
  short* G = GT + (size_t)bhc * 128 * 256;
  const int sr8 = l >> 3, sl8 = ((l & 7) ^ sr8) * 8;

#pragma unroll
  for (int j = 0; j < 8; ++j) {
    const int seg = w * 8 + j;
    gload16(kg + (size_t)(seg * 8 + sr8) * 64 + sl8, skT + seg * 512);
  }
#pragma unroll
  for (int j = 0; j < 4; ++j) {
    const int seg = w * 4 + j;
    gload16(vg + (size_t)(seg * 8 + sr8) * 64 + sl8, svt + seg * 512);
  }
  __syncthreads();

#pragma unroll
  for (int mi = 0; mi < 2; ++mi) {
    const int v0 = w * 32 + mi * 16;
    bf16x8 a[2];
#pragma unroll
    for (int ks = 0; ks < 2; ++ks)
      a[ks] = ld8(svt + (v0 + (l & 15)) * 64 + ((ks * 4 + (l >> 4)) ^ (l & 7)) * 8);
    f32x4 acc[16] = {};
#pragma unroll
    for (int nt = 0; nt < 16; ++nt)
#pragma unroll
      for (int ks = 0; ks < 2; ++ks) {
        bf16x8 b = ld8(skT + (nt * 16 + (l & 15)) * 64 + ((ks * 4 + (l >> 4)) ^ (l & 7)) * 8);
        acc[nt] = mfma16(a[ks], b, acc[nt]);
      }
#pragma unroll
    for (int nt = 0; nt < 16; ++nt)
#pragma unroll
      for (int r = 0; r < 4; ++r)
        G[(v0 + (l >> 4) * 4 + r) * 256 + nt * 16 + (l & 15)] = f2b(acc[nt][r]);
  }
}

// ---------------------------------------------------------------------------
// In-place exclusive prefix over chunks
// ---------------------------------------------------------------------------
__global__ void prefix_kernel(short* __restrict__ GT) {
  const int bh = blockIdx.x >> 4, slab = blockIdx.x & 15;
  short* base = GT + (size_t)bh * 32 * 32768 + slab * 2048 + threadIdx.x * 8;
  float acc[8] = {};
  short8 g = *(const short8*)base;
  for (int c = 0; c < 32; ++c) {
    short* p = base + (size_t)c * 32768;
    short8 gn = {};
    if (c < 31) gn = *(const short8*)(p + 32768);
    short8 s;
#pragma unroll
    for (int j = 0; j < 8; ++j) s[j] = f2b(acc[j]);
    *(short8*)p = s;
#pragma unroll
    for (int j = 0; j < 8; ++j) acc[j] += b2f(g[j]);
    g = gn;
  }
}

// ---------------------------------------------------------------------------
// Pass C: per (bh,chunk): O = tril(Q K^T) V + Q S, fused RMSNorm.
// ---------------------------------------------------------------------------
__launch_bounds__(256, 3)
__global__ void passC_kernel(const short* __restrict__ qf, const short* __restrict__ kf,
                             const short* __restrict__ vT, const short* __restrict__ ST,
                             const float* __restrict__ rms_w, short* __restrict__ o_n)
{
  const int bhc = blockIdx.x, bh = bhc >> 5, c = bhc & 31;
  const int tid = threadIdx.x, w = tid >> 6, l = tid & 63;
  __shared__ __align__(16) short bufA[64 * 256];
  __shared__ __align__(16) short bufV[64 * 64];
  __shared__ __align__(16) short attn[64 * 72];
  const short* qg = qf + ((size_t)bh * 2048 + c * 64) * 256;
  const short* kg = kf + ((size_t)bh * 2048 + c * 64) * 256;
  const short* vg = vT + (size_t)bhc * 128 * 64;
  const short* sg = ST + (size_t)bhc * 128 * 256;
  const int r0 = w * 16;
  const int sr8 = l >> 3, sl8 = ((l & 7) ^ sr8) * 8;
  const int l5 = l >> 5, s32 = l & 31;

#pragma unroll
  for (int j = 0; j < 8; ++j) {
    const int seg = w * 8 + j;
    const int row = seg * 2 + l5;
    gload16(kg + (size_t)row * 256 + (s32 ^ (row & 7)) * 8, bufA + seg * 512);
  }
  bf16x8 qreg[8];
#pragma unroll
  for (int ks = 0; ks < 8; ++ks)
    qreg[ks] = ld8(qg + (size_t)(r0 + (l & 15)) * 256 + ks * 32 + (l >> 4) * 8);

  __syncthreads();
  f32x4 s[4] = {};
#pragma unroll
  for (int ks = 0; ks < 8; ++ks) {
    const int rs = ((ks * 4 + (l >> 4)) ^ (l & 7)) * 8;
#pragma unroll
    for (int nt = 0; nt < 4; ++nt)
      s[nt] = mfma16(qreg[ks], ld8(bufA + (nt * 16 + (l & 15)) * 256 + rs), s[nt]);
  }
#pragma unroll
  for (int nt = 0; nt < 4; ++nt)
#pragma unroll
    for (int r = 0; r < 4; ++r) {
      int rr = r0 + (l >> 4) * 4 + r;
      int tt = nt * 16 + (l & 15);
      attn[rr * 72 + tt] = (tt <= rr) ? f2b(s[nt][r]) : (short)0;
    }

  f32x4 o[8] = {};
#pragma unroll
  for (int h = 0; h < 2; ++h) {
    __syncthreads();
#pragma unroll
    for (int j = 0; j < 8; ++j) {
      const int seg = w * 8 + j;
      const int row = seg * 2 + l5;
      gload16(sg + (size_t)(h * 64 + row) * 256 + (s32 ^ (row & 7)) * 8, bufA + seg * 512);
    }
#pragma unroll
    for (int j = 0; j < 2; ++j) {
      const int seg = w * 2 + j;
      const int row = seg * 8 + sr8;
      gload16(vg + (size_t)(h * 64 + row) * 64 + sl8, bufV + seg * 512);
    }
    __syncthreads();
#pragma unroll
    for (int ks = 0; ks < 2; ++ks) {
      bf16x8 a = ld8(attn + (r0 + (l & 15)) * 72 + ks * 32 + (l >> 4) * 8);
      const int rs = ((ks * 4 + (l >> 4)) ^ (l & 7)) * 8;
#pragma unroll
      for (int nt = 0; nt < 4; ++nt)
        o[h * 4 + nt] = mfma16(a, ld8(bufV + (nt * 16 + (l & 15)) * 64 + rs), o[h * 4 + nt]);
    }
#pragma unroll
    for (int ks = 0; ks < 8; ++ks) {
      const int rs = ((ks * 4 + (l >> 4)) ^ (l & 7)) * 8;
#pragma unroll
      for (int nt = 0; nt < 4; ++nt)
        o[h * 4 + nt] = mfma16(qreg[ks], ld8(bufA + (nt * 16 + (l & 15)) * 256 + rs), o[h * 4 + nt]);
    }
  }

  const int b = bh >> 3, hh = bh & 7;
#pragma unroll
  for (int r = 0; r < 4; ++r) {
    float ss = 0.f;
#pragma unroll
    for (int nt = 0; nt < 8; ++nt) ss += o[nt][r] * o[nt][r];
    ss += __shfl_xor(ss, 1);
    ss += __shfl_xor(ss, 2);
    ss += __shfl_xor(ss, 4);
    ss += __shfl_xor(ss, 8);
    float sc = rsqrtf(ss * (1.0f / 128.0f) + 1e-5f);
    int tok = c * 64 + r0 + (l >> 4) * 4 + r;
    size_t ob = ((size_t)b * 2048 + tok) * 1024 + hh * 128;
#pragma unroll
    for (int nt = 0; nt < 8; ++nt) {
      int vcol = nt * 16 + (l & 15);
      o_n[ob + vcol] = f2b(o[nt][r] * sc * rms_w[vcol]);
    }
  }
}

// ---------------------------------------------------------------------------
extern "C" void kernel_launch(void* const* d_in, const int* in_sizes, int n_in,
                              void* d_out, int out_size, void* d_ws, size_t ws_size,
                              hipStream_t stream)
{
  const float* x     = (const float*)d_in[0];
  const float* Wq    = (const float*)d_in[1];
  const float* Wk    = (const float*)d_in[2];
  const float* Wv    = (const float*)d_in[3];
  const float* Wo    = (const float*)d_in[4];
  const float* fmq_w = (const float*)d_in[5];
  const float* fmq_b = (const float*)d_in[6];
  const float* fmk_w = (const float*)d_in[7];
  const float* fmk_b = (const float*)d_in[8];
  const float* rms_w = (const float*)d_in[9];
  float* out = (float*)d_out;

  char* ws = (char*)d_ws;
  short* x_b  = (short*)(ws);                  // 16.78 MB  (reused as o_norm later)
  short* Wcat = (short*)(ws + 16777216);       //  6.29 MB
  short* Wo_b = (short*)(ws + 23068672);       //  2.10 MB
  short* qf   = (short*)(ws + 25165824);       // 33.55 MB
  short* kf   = (short*)(ws + 58720256);       // 33.55 MB
  short* kfT  = (short*)(ws + 92274688);       // 33.55 MB
  short* vT   = (short*)(ws + 125829120);      // 16.78 MB
  short* GT   = (short*)(ws + 142606336);      // 33.55 MB   (becomes S^T in-place)
  short* o_n  = x_b;                           // alias: x_b dead after QKV GEMM

  prep_kernel<<<5248, 256, 0, stream>>>(x, Wo, Wq, Wk, Wv, fmq_w, fmk_w,
                                        x_b, Wo_b, Wcat);
  gemm256<1><<<dim3(12, 32), 512, 0, stream>>>(x_b, Wcat, 1024, 3072, nullptr,
                                               fmq_b, fmk_b, qf, kf, kfT, vT);
  passA_kernel<<<1024, 256, 0, stream>>>(kfT, vT, GT);
  prefix_kernel<<<512, 256, 0, stream>>>(GT);
  passC_kernel<<<1024, 256, 0, stream>>>(qf, kf, vT, GT, rms_w, o_n);
  gemm256<0><<<dim3(4, 32), 512, 0, stream>>>(o_n, Wo_b, 1024, 1024, out,
                                              nullptr, nullptr, nullptr, nullptr,
                                              nullptr, nullptr);
}

// Round 10
// 345.428 us; speedup vs baseline: 1.3525x; 1.0286x over previous
//
#include <hip/hip_runtime.h>
#include <cstdint>
#include <cstddef>

#define DEV __device__ __forceinline__

typedef __attribute__((ext_vector_type(8))) short   short8;
typedef __attribute__((ext_vector_type(4))) short   sshort4;
typedef __attribute__((ext_vector_type(8))) __bf16  bf16x8;
typedef __attribute__((ext_vector_type(4))) float   f32x4;

typedef void as1_void __attribute__((address_space(1)));
typedef void as3_void __attribute__((address_space(3)));

DEV short f2b(float f) {
  unsigned u = __float_as_uint(f);
  unsigned r = (u + 0x7fffu + ((u >> 16) & 1u)) >> 16;
  return (short)r;
}
DEV float b2f(short s) {
  return __uint_as_float(((unsigned)(unsigned short)s) << 16);
}

DEV void gload16(const void* g, void* l) {
  __builtin_amdgcn_global_load_lds((as1_void*)g, (as3_void*)l, 16, 0, 0);
}

DEV bf16x8 ld8(const short* p) { return *reinterpret_cast<const bf16x8*>(p); }

DEV f32x4 mfma16(bf16x8 a, bf16x8 b, f32x4 c) {
  return __builtin_amdgcn_mfma_f32_16x16x32_bf16(a, b, c, 0, 0, 0);
}

// ---------------------------------------------------------------------------
// Fused prep: x->bf16, Wo->bf16, Wv->bf16 (into Wcat rows 2048+), and
// eff_weights (hedgehog fold) for Wcat rows 0..2047. One dispatch.
// ---------------------------------------------------------------------------
__global__ void prep_kernel(const float* __restrict__ x, const float* __restrict__ Wo,
                            const float* __restrict__ Wq, const float* __restrict__ Wk,
                            const float* __restrict__ Wv,
                            const float* __restrict__ fmq_w, const float* __restrict__ fmk_w,
                            short* __restrict__ x_b, short* __restrict__ Wo_b,
                            short* __restrict__ Wcat)
{
  const int blk = blockIdx.x;
  const int tid = threadIdx.x;
  if (blk < 5120) {
    const float* src;
    short* dst;
    int i;
    if (blk < 4096)      { src = x;  dst = x_b;            i = (blk * 256 + tid) * 8; }
    else if (blk < 4608) { src = Wo; dst = Wo_b;           i = ((blk - 4096) * 256 + tid) * 8; }
    else                 { src = Wv; dst = Wcat + 2097152; i = ((blk - 4608) * 256 + tid) * 8; }
    float4 a = *(const float4*)(src + i);
    float4 b = *(const float4*)(src + i + 4);
    short8 o;
    o[0] = f2b(a.x); o[1] = f2b(a.y); o[2] = f2b(a.z); o[3] = f2b(a.w);
    o[4] = f2b(b.x); o[5] = f2b(b.y); o[6] = f2b(b.z); o[7] = f2b(b.w);
    *(short8*)(dst + i) = o;
  } else {
    __shared__ float fm[16 * 128];
    const int eb = blk - 5120;
    const int sel = eb >> 6, h = (eb >> 3) & 7, eg = eb & 7;
    const float* W   = sel ? Wk : Wq;
    const float* fmw = sel ? fmk_w : fmq_w;
    const int e0 = eg * 16;
    for (int i = tid; i < 2048; i += 256) fm[i] = fmw[e0 * 128 + i];
    __syncthreads();
    float acc[16][4] = {};
    for (int d = 0; d < 128; d += 4) {
      f32x4 w0 = *(const f32x4*)(W + (size_t)(h * 128 + d + 0) * 1024 + tid * 4);
      f32x4 w1 = *(const f32x4*)(W + (size_t)(h * 128 + d + 1) * 1024 + tid * 4);
      f32x4 w2 = *(const f32x4*)(W + (size_t)(h * 128 + d + 2) * 1024 + tid * 4);
      f32x4 w3 = *(const f32x4*)(W + (size_t)(h * 128 + d + 3) * 1024 + tid * 4);
#pragma unroll
      for (int e = 0; e < 16; ++e) {
        f32x4 fv = *(const f32x4*)&fm[e * 128 + d];
#pragma unroll
        for (int c = 0; c < 4; ++c)
          acc[e][c] += fv[0] * w0[c] + fv[1] * w1[c] + fv[2] * w2[c] + fv[3] * w3[c];
      }
    }
#pragma unroll
    for (int e = 0; e < 16; ++e) {
      sshort4 o;
#pragma unroll
      for (int c = 0; c < 4; ++c) o[c] = f2b(acc[e][c]);
      *(sshort4*)(Wcat + (size_t)(sel * 1024 + h * 128 + e0 + e) * 1024 + tid * 4) = o;
    }
  }
}

// ---------------------------------------------------------------------------
// 256x256 8-phase bf16 GEMM (QKV, EPI=1). Unchanged from round 7.
// ---------------------------------------------------------------------------
template<int EPI>
__launch_bounds__(512, 2)
__global__ void gemm256(const short* __restrict__ A, const short* __restrict__ B,
                        const int K, const int N, float* __restrict__ C,
                        const float* __restrict__ qb, const float* __restrict__ kb,
                        short* __restrict__ qf, short* __restrict__ kf,
                        short* __restrict__ kfT, short* __restrict__ vT)
{
  __shared__ __align__(16) short lds[65536];
  float* ep = (float*)lds;

  const int tid = threadIdx.x;
  const int w = tid >> 6, l = tid & 63;
  const int wr = w >> 2, wc = w & 3;

  const int nbx = gridDim.x;
  const int orig = blockIdx.y * nbx + blockIdx.x;
  const int cpx = (nbx * gridDim.y) >> 3;
  const int wg = (orig & 7) * cpx + (orig >> 3);
  const int m0 = (wg / nbx) * 256, n0 = (wg % nbx) * 256;

  const int srow = tid >> 3;
  const int scol = ((tid & 7) ^ (srow & 7)) * 8;
  const int wbase = w * 8;

  f32x4 acc[8][4] = {};
  bf16x8 af[4][2];
  bf16x8 bg[2][2][2];

  auto STG = [&](const short* src, int g0, int p, int aoff, int R, int t) {
    gload16(src + (size_t)(g0 + R + srow) * K + t * 64 + scol,
            lds + p * 32768 + aoff + (R + wbase) * 64);
  };

#pragma unroll
  for (int R = 0; R < 256; R += 64) {
    STG(A, m0, 0, 0, R, 0);
    STG(B, n0, 0, 16384, R, 0);
    STG(A, m0, 1, 0, R, 1);
    STG(B, n0, 1, 16384, R, 1);
  }
  asm volatile("s_waitcnt vmcnt(0)" ::: "memory");
  __builtin_amdgcn_s_barrier();

#define PHASE(p, q, DOLDA, DOLDB, STAGES, TAIL) { \
    if (DOLDA) { \
      _Pragma("unroll") \
      for (int m = 0; m < 4; ++m) { \
        const int r = wr * 128 + ((q) >> 1) * 64 + m * 16 + (l & 15); \
        _Pragma("unroll") \
        for (int kk = 0; kk < 2; ++kk) \
          af[m][kk] = ld8(lds + (p) * 32768 + r * 64 + ((kk * 4 + (l >> 4)) ^ (r & 7)) * 8); \
      } \
    } \
    if (DOLDB) { \
      _Pragma("unroll") \
      for (int n = 0; n < 2; ++n) { \
        const int r = wc * 64 + ((q) & 1) * 32 + n * 16 + (l & 15); \
        _Pragma("unroll") \
        for (int kk = 0; kk < 2; ++kk) \
          bg[(q) & 1][n][kk] = ld8(lds + (p) * 32768 + 16384 + r * 64 + ((kk * 4 + (l >> 4)) ^ (r & 7)) * 8); \
      } \
    } \
    STAGES; \
    __builtin_amdgcn_s_barrier(); \
    asm volatile("s_waitcnt lgkmcnt(0)" ::: "memory"); \
    __builtin_amdgcn_sched_barrier(0); \
    __builtin_amdgcn_s_setprio(1); \
    _Pragma("unroll") \
    for (int m = 0; m < 4; ++m) \
      _Pragma("unroll") \
      for (int n = 0; n < 2; ++n) \
        _Pragma("unroll") \
        for (int kk = 0; kk < 2; ++kk) \
          acc[((q) >> 1) * 4 + m][((q) & 1) * 2 + n] = \
            mfma16(af[m][kk], bg[(q) & 1][n][kk], acc[((q) >> 1) * 4 + m][((q) & 1) * 2 + n]); \
    __builtin_amdgcn_s_setprio(0); \
    TAIL; \
    __builtin_amdgcn_s_barrier(); \
  }

  const int NI = K >> 7;
  for (int i = 0; i < NI; ++i) {
    const int t1 = 2 * i + 1, t2 = 2 * i + 2, t3 = 2 * i + 3;
    const bool sE = (i < NI - 1), sL = (i > 0);
    PHASE(0, 0, 1, 1, {
      if (sL) { STG(A, m0, 1, 0, 64, t1); STG(A, m0, 1, 0, 192, t1);
                STG(B, n0, 1, 16384, 0, t1); STG(B, n0, 1, 16384, 64, t1); } }, {});
    PHASE(0, 1, 0, 1, {
      if (sL) { STG(B, n0, 1, 16384, 128, t1); STG(B, n0, 1, 16384, 192, t1); } }, {});
    PHASE(0, 2, 1, 0, {
      if (sE) { STG(A, m0, 0, 0, 0, t2); STG(A, m0, 0, 0, 128, t2); } }, {});
    PHASE(0, 3, 0, 0, {}, {
      if (i == NI - 1) { asm volatile("s_waitcnt vmcnt(0)" ::: "memory"); }
      else             { asm volatile("s_waitcnt vmcnt(2)" ::: "memory"); } });
    PHASE(1, 0, 1, 1, {
      if (sE) { STG(A, m0, 0, 0, 64, t2); STG(A, m0, 0, 0, 192, t2); } }, {});
    PHASE(1, 1, 0, 1, {
      if (sE) { STG(B, n0, 0, 16384, 0, t2); STG(B, n0, 0, 16384, 64, t2); } }, {});
    PHASE(1, 2, 1, 0, {
      if (sE) { STG(B, n0, 0, 16384, 128, t2); STG(B, n0, 0, 16384, 192, t2); } }, {});
    PHASE(1, 3, 0, 0, {
      if (sE) { STG(A, m0, 1, 0, 0, t3); STG(A, m0, 1, 0, 128, t3); } }, {
      asm volatile("s_waitcnt vmcnt(2)" ::: "memory"); });
  }
#undef PHASE

  const int seg = (EPI == 1) ? (n0 >> 10) : 0;
  const int b = m0 >> 11, tok0 = m0 & 2047, c0 = tok0 >> 6;
  const int hbase = (n0 & 1023) >> 7;
  const int bh0 = b * 8 + hbase;

#pragma unroll
  for (int h = 0; h < 4; ++h) {
    __syncthreads();
    if (wr == (h >> 1)) {
      const int mbase = (h & 1) * 4;
#pragma unroll
      for (int n = 0; n < 4; ++n) {
        const int cl = wc * 64 + n * 16 + (l & 15);
        float bb = 0.f;
        if constexpr (EPI == 1) bb = (seg == 0) ? qb[cl & 127] : (seg == 1) ? kb[cl & 127] : 0.f;
#pragma unroll
        for (int m4 = 0; m4 < 4; ++m4)
#pragma unroll
          for (int r = 0; r < 4; ++r) {
            const int rl = m4 * 16 + (l >> 4) * 4 + r;
            ep[rl * 264 + (cl ^ ((rl & 3) << 2))] = acc[mbase + m4][n][r] + bb;
          }
      }
    }
    __syncthreads();

    if constexpr (EPI == 0) {
#pragma unroll
      for (int it = 0; it < 8; ++it) {
        const int tl = it * 8 + (tid >> 6);
        const int cc4 = (tid & 63) * 4;
        f32x4 v4 = *(const f32x4*)&ep[tl * 264 + (cc4 ^ ((tl & 3) << 2))];
        *(f32x4*)(C + (size_t)(m0 + h * 64 + tl) * N + n0 + cc4) = v4;
      }
    } else {
      const int cc = c0 + h;
      if (seg <= 1) {
        short* dst = (seg == 0) ? qf : kf;
        const float sc = (seg == 0) ? 0.0625f : 1.0f;
#pragma unroll
        for (int it = 0; it < 8; ++it) {
          const int tl = it * 8 + (tid >> 6);
          const int cc4 = (tid & 63) * 4;
          f32x4 y4 = *(const f32x4*)&ep[tl * 264 + (cc4 ^ ((tl & 3) << 2))];
          sshort4 sp, sm;
#pragma unroll
          for (int j = 0; j < 4; ++j) {
            sp[j] = f2b(__expf(y4[j]) * sc);
            sm[j] = f2b(__expf(-y4[j]) * sc);
          }
          const int hh = cc4 >> 7, e = cc4 & 127;
          short* rowp = dst + ((size_t)(bh0 + hh) * 2048 + tok0 + h * 64 + tl) * 256;
          *(sshort4*)(rowp + e)       = sp;
          *(sshort4*)(rowp + 128 + e) = sm;
        }
        if (seg == 1) {
#pragma unroll
          for (int p2 = 0; p2 < 8; ++p2) {
            const int idx = p2 * 512 + tid;
            const int er = idx >> 3, oct = (idx & 7) * 8;
            const int hh = er >> 8, rr = er & 255, e = rr & 127, sg = rr >> 7;
            const int cgc = hh * 128 + e;
            short8 o;
#pragma unroll
            for (int ii = 0; ii < 8; ++ii) {
              float y = ep[(oct + ii) * 264 + (cgc ^ (((oct + ii) & 3) << 2))];
              o[ii] = f2b(__expf(sg ? -y : y));
            }
            *(short8*)(kfT + ((size_t)(bh0 + hh) * 32 + cc) * 16384 + (size_t)rr * 64 + oct) = o;
          }
        }
      } else {
#pragma unroll
        for (int p2 = 0; p2 < 4; ++p2) {
          const int idx = p2 * 512 + tid;
          const int er = idx >> 3, oct = (idx & 7) * 8;
          const int hh = er >> 7, vv = er & 127;
          short8 o;
#pragma unroll
          for (int ii = 0; ii < 8; ++ii)
            o[ii] = f2b(ep[(oct + ii) * 264 + (er ^ (((oct + ii) & 3) << 2))]);
          *(short8*)(vT + ((size_t)(bh0 + hh) * 32 + cc) * 8192 + (size_t)vv * 64 + oct) = o;
        }
      }
    }
  }
}

// ---------------------------------------------------------------------------
// Wo GEMM: C[8192][1024] = A @ B^T, tile 256x128 -> grid 32x8 = 256 blocks
// (exactly one full round on 256 CUs). 8 waves as 4(M)x2(N), per-wave 64x64.
// BK=64, dbuf LDS 96KB. Uniform staging schedule (race-audited):
//   tile j staged at: ph3(j-2): A0,A64 | ph0(j-1): A128,A192 | ph1(j-1): B0
//   | ph2(j-1): B64.  vmcnt(2) at each ph3 tail (vmcnt(0) at j=NT-2).
// ---------------------------------------------------------------------------
__launch_bounds__(512, 2)
__global__ void gemm_wo(const short* __restrict__ A, const short* __restrict__ B,
                        float* __restrict__ C)
{
  const int K = 1024, N = 1024, NT = 16;
  __shared__ __align__(16) short lds[49152];   // 2 bufs x (A 16384 | B 8192)
  float* ep = (float*)lds;

  const int tid = threadIdx.x;
  const int w = tid >> 6, l = tid & 63;
  const int wr = w >> 1, wc = w & 1;           // 4(M) x 2(N) wave grid

  // XCD-aware bijective swizzle, nwg = 256
  const int orig = blockIdx.y * 8 + blockIdx.x;
  const int wg = (orig & 7) * 32 + (orig >> 3);
  const int m0 = (wg >> 3) * 256, n0 = (wg & 7) * 128;

  const int srow = tid >> 3;
  const int scol = ((tid & 7) ^ (srow & 7)) * 8;
  const int wbase = w * 8;

  f32x4 acc[4][4] = {};
  bf16x8 af[2][2];
  bf16x8 bg[2][2][2];

  auto STG = [&](const short* src, int g0, int p, int aoff, int R, int t) {
    gload16(src + (size_t)(g0 + R + srow) * K + t * 64 + scol,
            lds + p * 24576 + aoff + (R + wbase) * 64);
  };

  // prologue: tiles 0,1 fully staged
#pragma unroll
  for (int p = 0; p < 2; ++p) {
    STG(A, m0, p, 0, 0, p);   STG(A, m0, p, 0, 64, p);
    STG(A, m0, p, 0, 128, p); STG(A, m0, p, 0, 192, p);
    STG(B, n0, p, 16384, 0, p); STG(B, n0, p, 16384, 64, p);
  }
  asm volatile("s_waitcnt vmcnt(0)" ::: "memory");
  __builtin_amdgcn_s_barrier();

#define PH(p, q, DOLDA, DOLDB, STAGES, TAIL) { \
    if (DOLDA) { \
      _Pragma("unroll") \
      for (int m = 0; m < 2; ++m) { \
        const int r = wr * 64 + ((q) >> 1) * 32 + m * 16 + (l & 15); \
        _Pragma("unroll") \
        for (int kk = 0; kk < 2; ++kk) \
          af[m][kk] = ld8(lds + (p) * 24576 + r * 64 + ((kk * 4 + (l >> 4)) ^ (r & 7)) * 8); \
      } \
    } \
    if (DOLDB) { \
      _Pragma("unroll") \
      for (int n = 0; n < 2; ++n) { \
        const int r = wc * 64 + ((q) & 1) * 32 + n * 16 + (l & 15); \
        _Pragma("unroll") \
        for (int kk = 0; kk < 2; ++kk) \
          bg[(q) & 1][n][kk] = ld8(lds + (p) * 24576 + 16384 + r * 64 + ((kk * 4 + (l >> 4)) ^ (r & 7)) * 8); \
      } \
    } \
    STAGES; \
    __builtin_amdgcn_s_barrier(); \
    asm volatile("s_waitcnt lgkmcnt(0)" ::: "memory"); \
    __builtin_amdgcn_sched_barrier(0); \
    __builtin_amdgcn_s_setprio(1); \
    _Pragma("unroll") \
    for (int m = 0; m < 2; ++m) \
      _Pragma("unroll") \
      for (int n = 0; n < 2; ++n) \
        _Pragma("unroll") \
        for (int kk = 0; kk < 2; ++kk) \
          acc[((q) >> 1) * 2 + m][((q) & 1) * 2 + n] = \
            mfma16(af[m][kk], bg[(q) & 1][n][kk], acc[((q) >> 1) * 2 + m][((q) & 1) * 2 + n]); \
    __builtin_amdgcn_s_setprio(0); \
    TAIL; \
    __builtin_amdgcn_s_barrier(); \
  }

  for (int i = 0; i < NT; ++i) {
    const int p = i & 1;
    const bool sM = (i >= 1) && (i + 1 < NT);  // stage tile i+1 (buf p^1)
    const bool sP = (i + 2 < NT);              // stage tile i+2 (buf p)
    PH(p, 0, 1, 1, {
      if (sM) { STG(A, m0, p ^ 1, 0, 128, i + 1); STG(A, m0, p ^ 1, 0, 192, i + 1); } }, {});
    PH(p, 1, 0, 1, {
      if (sM) { STG(B, n0, p ^ 1, 16384, 0, i + 1); } }, {});
    PH(p, 2, 1, 0, {
      if (sM) { STG(B, n0, p ^ 1, 16384, 64, i + 1); } }, {});
    PH(p, 3, 0, 0, {
      if (sP) { STG(A, m0, p, 0, 0, i + 2); STG(A, m0, p, 0, 64, i + 2); } }, {
      if (i < NT - 2)       { asm volatile("s_waitcnt vmcnt(2)" ::: "memory"); }
      else if (i == NT - 2) { asm volatile("s_waitcnt vmcnt(0)" ::: "memory"); } });
  }
#undef PH

  // epilogue: f32 [64][132] LDS-staged, 4 bands of 64 rows
#pragma unroll
  for (int h = 0; h < 4; ++h) {
    __syncthreads();
    if (wr == h) {
#pragma unroll
      for (int ni = 0; ni < 4; ++ni) {
        const int cl = wc * 64 + ni * 16 + (l & 15);
#pragma unroll
        for (int mi = 0; mi < 4; ++mi)
#pragma unroll
          for (int r = 0; r < 4; ++r) {
            const int rl = mi * 16 + (l >> 4) * 4 + r;
            ep[rl * 132 + (cl ^ ((rl & 3) << 2))] = acc[mi][ni][r];
          }
      }
    }
    __syncthreads();
#pragma unroll
    for (int it = 0; it < 4; ++it) {
      const int tl = it * 16 + (tid >> 5);
      const int q = tid & 31;
      f32x4 v4 = *(const f32x4*)&ep[tl * 132 + ((q * 4) ^ ((tl & 3) << 2))];
      *(f32x4*)(C + (size_t)(m0 + h * 64 + tl) * N + n0 + q * 4) = v4;
    }
  }
}

// ---------------------------------------------------------------------------
// Pass A: per (bh,chunk) GT = V^T @ K -> [128 v][256 d] bf16 (LDS-staged)
// ---------------------------------------------------------------------------
__launch_bounds__(256, 3)
__global__ void passA_kernel(const short* __restrict__ kfT, const short* __restrict__ vT,
                             short* __restrict__ GT)
{
  const int bhc = blockIdx.x;
  const int tid = threadIdx.x, w = tid >> 6, l = tid & 63;
  __shared__ __align__(16) short skT[256 * 64];
  __shared__ __align__(16) short svt[128 * 64];
  const short* kg = kfT + (size_t)bhc * 256 * 64;
  const short* vg = vT  + (size_t)bhc * 128 * 64;
  short* G = GT + (size_t)bhc * 128 * 256;
  const int sr8 = l >> 3, sl8 = ((l & 7) ^ sr8) * 8;

#pragma unroll
  for (int j = 0; j < 8; ++j) {
    const int seg = w * 8 + j;
    gload16(kg + (size_t)(seg * 8 + sr8) * 64 + sl8, skT + seg * 512);
  }
#pragma unroll
  for (int j = 0; j < 4; ++j) {
    const int seg = w * 4 + j;
    gload16(vg + (size_t)(seg * 8 + sr8) * 64 + sl8, svt + seg * 512);
  }
  __syncthreads();

#pragma unroll
  for (int mi = 0; mi < 2; ++mi) {
    const int v0 = w * 32 + mi * 16;
    bf16x8 a[2];
#pragma unroll
    for (int ks = 0; ks < 2; ++ks)
      a[ks] = ld8(svt + (v0 + (l & 15)) * 64 + ((ks * 4 + (l >> 4)) ^ (l & 7)) * 8);
    f32x4 acc[16] = {};
#pragma unroll
    for (int nt = 0; nt < 16; ++nt)
#pragma unroll
      for (int ks = 0; ks < 2; ++ks) {
        bf16x8 b = ld8(skT + (nt * 16 + (l & 15)) * 64 + ((ks * 4 + (l >> 4)) ^ (l & 7)) * 8);
        acc[nt] = mfma16(a[ks], b, acc[nt]);
      }
#pragma unroll
    for (int nt = 0; nt < 16; ++nt)
#pragma unroll
      for (int r = 0; r < 4; ++r)
        G[(v0 + (l >> 4) * 4 + r) * 256 + nt * 16 + (l & 15)] = f2b(acc[nt][r]);
  }
}

// ---------------------------------------------------------------------------
// In-place exclusive prefix over chunks
// ---------------------------------------------------------------------------
__global__ void prefix_kernel(short* __restrict__ GT) {
  const int bh = blockIdx.x >> 4, slab = blockIdx.x & 15;
  short* base = GT + (size_t)bh * 32 * 32768 + slab * 2048 + threadIdx.x * 8;
  float acc[8] = {};
  short8 g = *(const short8*)base;
  for (int c = 0; c < 32; ++c) {
    short* p = base + (size_t)c * 32768;
    short8 gn = {};
    if (c < 31) gn = *(const short8*)(p + 32768);
    short8 s;
#pragma unroll
    for (int j = 0; j < 8; ++j) s[j] = f2b(acc[j]);
    *(short8*)p = s;
#pragma unroll
    for (int j = 0; j < 8; ++j) acc[j] += b2f(g[j]);
    g = gn;
  }
}

// ---------------------------------------------------------------------------
// Pass C: per (bh,chunk): O = tril(Q K^T) V + Q S, fused RMSNorm.
// ---------------------------------------------------------------------------
__launch_bounds__(256, 3)
__global__ void passC_kernel(const short* __restrict__ qf, const short* __restrict__ kf,
                             const short* __restrict__ vT, const short* __restrict__ ST,
                             const float* __restrict__ rms_w, short* __restrict__ o_n)
{
  const int bhc = blockIdx.x, bh = bhc >> 5, c = bhc & 31;
  const int tid = threadIdx.x, w = tid >> 6, l = tid & 63;
  __shared__ __align__(16) short bufA[64 * 256];
  __shared__ __align__(16) short bufV[64 * 64];
  __shared__ __align__(16) short attn[64 * 72];
  const short* qg = qf + ((size_t)bh * 2048 + c * 64) * 256;
  const short* kg = kf + ((size_t)bh * 2048 + c * 64) * 256;
  const short* vg = vT + (size_t)bhc * 128 * 64;
  const short* sg = ST + (size_t)bhc * 128 * 256;
  const int r0 = w * 16;
  const int sr8 = l >> 3, sl8 = ((l & 7) ^ sr8) * 8;
  const int l5 = l >> 5, s32 = l & 31;

#pragma unroll
  for (int j = 0; j < 8; ++j) {
    const int seg = w * 8 + j;
    const int row = seg * 2 + l5;
    gload16(kg + (size_t)row * 256 + (s32 ^ (row & 7)) * 8, bufA + seg * 512);
  }
  bf16x8 qreg[8];
#pragma unroll
  for (int ks = 0; ks < 8; ++ks)
    qreg[ks] = ld8(qg + (size_t)(r0 + (l & 15)) * 256 + ks * 32 + (l >> 4) * 8);

  __syncthreads();
  f32x4 s[4] = {};
#pragma unroll
  for (int ks = 0; ks < 8; ++ks) {
    const int rs = ((ks * 4 + (l >> 4)) ^ (l & 7)) * 8;
#pragma unroll
    for (int nt = 0; nt < 4; ++nt)
      s[nt] = mfma16(qreg[ks], ld8(bufA + (nt * 16 + (l & 15)) * 256 + rs), s[nt]);
  }
#pragma unroll
  for (int nt = 0; nt < 4; ++nt)
#pragma unroll
    for (int r = 0; r < 4; ++r) {
      int rr = r0 + (l >> 4) * 4 + r;
      int tt = nt * 16 + (l & 15);
      attn[rr * 72 + tt] = (tt <= rr) ? f2b(s[nt][r]) : (short)0;
    }

  f32x4 o[8] = {};
#pragma unroll
  for (int h = 0; h < 2; ++h) {
    __syncthreads();
#pragma unroll
    for (int j = 0; j < 8; ++j) {
      const int seg = w * 8 + j;
      const int row = seg * 2 + l5;
      gload16(sg + (size_t)(h * 64 + row) * 256 + (s32 ^ (row & 7)) * 8, bufA + seg * 512);
    }
#pragma unroll
    for (int j = 0; j < 2; ++j) {
      const int seg = w * 2 + j;
      const int row = seg * 8 + sr8;
      gload16(vg + (size_t)(h * 64 + row) * 64 + sl8, bufV + seg * 512);
    }
    __syncthreads();
#pragma unroll
    for (int ks = 0; ks < 2; ++ks) {
      bf16x8 a = ld8(attn + (r0 + (l & 15)) * 72 + ks * 32 + (l >> 4) * 8);
      const int rs = ((ks * 4 + (l >> 4)) ^ (l & 7)) * 8;
#pragma unroll
      for (int nt = 0; nt < 4; ++nt)
        o[h * 4 + nt] = mfma16(a, ld8(bufV + (nt * 16 + (l & 15)) * 64 + rs), o[h * 4 + nt]);
    }
#pragma unroll
    for (int ks = 0; ks < 8; ++ks) {
      const int rs = ((ks * 4 + (l >> 4)) ^ (l & 7)) * 8;
#pragma unroll
      for (int nt = 0; nt < 4; ++nt)
        o[h * 4 + nt] = mfma16(qreg[ks], ld8(bufA + (nt * 16 + (l & 15)) * 256 + rs), o[h * 4 + nt]);
    }
  }

  const int b = bh >> 3, hh = bh & 7;
#pragma unroll
  for (int r = 0; r < 4; ++r) {
    float ss = 0.f;
#pragma unroll
    for (int nt = 0; nt < 8; ++nt) ss += o[nt][r] * o[nt][r];
    ss += __shfl_xor(ss, 1);
    ss += __shfl_xor(ss, 2);
    ss += __shfl_xor(ss, 4);
    ss += __shfl_xor(ss, 8);
    float sc = rsqrtf(ss * (1.0f / 128.0f) + 1e-5f);
    int tok = c * 64 + r0 + (l >> 4) * 4 + r;
    size_t ob = ((size_t)b * 2048 + tok) * 1024 + hh * 128;
#pragma unroll
    for (int nt = 0; nt < 8; ++nt) {
      int vcol = nt * 16 + (l & 15);
      o_n[ob + vcol] = f2b(o[nt][r] * sc * rms_w[vcol]);
    }
  }
}

// ---------------------------------------------------------------------------
extern "C" void kernel_launch(void* const* d_in, const int* in_sizes, int n_in,
                              void* d_out, int out_size, void* d_ws, size_t ws_size,
                              hipStream_t stream)
{
  const float* x     = (const float*)d_in[0];
  const float* Wq    = (const float*)d_in[1];
  const float* Wk    = (const float*)d_in[2];
  const float* Wv    = (const float*)d_in[3];
  const float* Wo    = (const float*)d_in[4];
  const float* fmq_w = (const float*)d_in[5];
  const float* fmq_b = (const float*)d_in[6];
  const float* fmk_w = (const float*)d_in[7];
  const float* fmk_b = (const float*)d_in[8];
  const float* rms_w = (const float*)d_in[9];
  float* out = (float*)d_out;

  char* ws = (char*)d_ws;
  short* x_b  = (short*)(ws);                  // 16.78 MB  (reused as o_norm later)
  short* Wcat = (short*)(ws + 16777216);       //  6.29 MB
  short* Wo_b = (short*)(ws + 23068672);       //  2.10 MB
  short* qf   = (short*)(ws + 25165824);       // 33.55 MB
  short* kf   = (short*)(ws + 58720256);       // 33.55 MB
  short* kfT  = (short*)(ws + 92274688);       // 33.55 MB
  short* vT   = (short*)(ws + 125829120);      // 16.78 MB
  short* GT   = (short*)(ws + 142606336);      // 33.55 MB   (becomes S^T in-place)
  short* o_n  = x_b;                           // alias: x_b dead after QKV GEMM

  prep_kernel<<<5248, 256, 0, stream>>>(x, Wo, Wq, Wk, Wv, fmq_w, fmk_w,
                                        x_b, Wo_b, Wcat);
  gemm256<1><<<dim3(12, 32), 512, 0, stream>>>(x_b, Wcat, 1024, 3072, nullptr,
                                               fmq_b, fmk_b, qf, kf, kfT, vT);
  passA_kernel<<<1024, 256, 0, stream>>>(kfT, vT, GT);
  prefix_kernel<<<512, 256, 0, stream>>>(GT);
  passC_kernel<<<1024, 256, 0, stream>>>(qf, kf, vT, GT, rms_w, o_n);
  gemm_wo<<<dim3(8, 32), 512, 0, stream>>>(o_n, Wo_b, out);
}